// Round 7
// baseline (910.765 us; speedup 1.0000x reference)
//
#include <hip/hip_runtime.h>
#include <hip/hip_bf16.h>
#include <math.h>

#define B_   32
#define L_   2048
#define H_   8
#define DMET 16
#define SDIM 27
#define DM   256
#define NL   4
#define DS   64
#define TE   256
#define LT   2055          // L + H - 1
#define LTR  2176          // 17*128: padded l for Ub/Ybt
#define TCH  128           // chunk length
#define NC   17            // chunks per sequence
#define COLS 544           // B_ * NC
#define NTOT (B_ * LT)

typedef __attribute__((ext_vector_type(8))) short short8;
typedef __attribute__((ext_vector_type(4))) short short4v;
typedef __attribute__((ext_vector_type(4))) float floatx4;

// fast sigmoid: 1/(1+2^(-x*log2 e)) via v_exp_f32 + v_rcp_f32.
__device__ __forceinline__ float sigmoidf_(float x) {
    float e = __builtin_amdgcn_exp2f(-1.4426950408889634f * x);
    return __builtin_amdgcn_rcpf(1.0f + e);
}

// tanh-gelu in sigmoid form: 0.5*(1+tanh(z)) == sigmoid(2z) exactly.
__device__ __forceinline__ float gelu_tanh(float x) {
    float inner = 1.5957691216057308f * fmaf(0.044715f * x * x, x, x);
    return x * sigmoidf_(inner);
}

// hardware exp/sin/cos (revolutions, fract-reduced).
__device__ __forceinline__ float fexp_(float x) {
    return __builtin_amdgcn_exp2f(1.4426950408889634f * x);
}
__device__ __forceinline__ float fsin_(float ph) {
    float r = ph * 0.15915494309189535f;
    r = r - floorf(r);
    return __builtin_amdgcn_sinf(r);
}
__device__ __forceinline__ float fcos_(float ph) {
    float r = ph * 0.15915494309189535f;
    r = r - floorf(r);
    return __builtin_amdgcn_cosf(r);
}

__device__ __forceinline__ short bfs(float x) {
    __hip_bfloat16 h = __float2bfloat16(x);
    return *(short*)&h;
}

__device__ __forceinline__ float sbf(short s) {
    unsigned u = ((unsigned)(unsigned short)s) << 16;
    return __uint_as_float(u);
}

__device__ __forceinline__ void glds16(const void* g, void* l) {
    __builtin_amdgcn_global_load_lds(
        (const __attribute__((address_space(1))) unsigned*)g,
        (__attribute__((address_space(3))) unsigned*)l, 16, 0, 0);
}

// counted-vmcnt fence + full barrier (for glds-based kernels)
#define BARV(n) do {                                                          \
    asm volatile("s_waitcnt vmcnt(" #n ") lgkmcnt(0)" ::: "memory");          \
    __builtin_amdgcn_s_barrier();                                             \
    asm volatile("" ::: "memory");                                            \
} while (0)

// lgkm-only fence + barrier (ds visibility; vmem loads stay in flight)
#define BARL do {                                                             \
    asm volatile("s_waitcnt lgkmcnt(0)" ::: "memory");                        \
    __builtin_amdgcn_sched_barrier(0);                                        \
    __builtin_amdgcn_s_barrier();                                             \
    asm volatile("" ::: "memory");                                            \
} while (0)

// ---------------------------------------------------------------------------
// 1) time MLP
// ---------------------------------------------------------------------------
__global__ __launch_bounds__(256) void time_mlp_kernel(
    const float* __restrict__ t, const float* __restrict__ freqs,
    const float* __restrict__ phases,
    const float* __restrict__ W1, const float* __restrict__ b1,
    const float* __restrict__ W2, const float* __restrict__ b2,
    float* __restrict__ tb) {
    int b = blockIdx.x;
    int tid = threadIdx.x;
    __shared__ float f[TE];
    __shared__ float hid[2 * TE];
    float tv = t[b];
    f[tid] = cosf(fmaf(tv, freqs[tid], phases[tid])) * 1.4142135623730951f;
    __syncthreads();
    float a0 = b1[tid], a1 = b1[tid + TE];
    for (int k = 0; k < TE; ++k) {
        float fk = f[k];
        a0 = fmaf(fk, W1[k * 2 * TE + tid], a0);
        a1 = fmaf(fk, W1[k * 2 * TE + tid + TE], a1);
    }
    hid[tid]      = a0 * sigmoidf_(a0);
    hid[tid + TE] = a1 * sigmoidf_(a1);
    __syncthreads();
    float acc = b2[tid];
    for (int j = 0; j < 2 * TE; ++j)
        acc = fmaf(hid[j], W2[j * DM + tid], acc);
    tb[b * DM + tid] = acc;
}

// ---------------------------------------------------------------------------
// 1b) out_W [NL][256][512] fp32 -> Wtp bf16 [NL][512 permuted cols][256 k]
// ---------------------------------------------------------------------------
__global__ __launch_bounds__(256) void wt_prep_kernel(
    const float* __restrict__ out_W, __hip_bfloat16* __restrict__ Wtp) {
    int bid = blockIdx.x;
    int layer = bid >> 8, k = bid & 255;
    int e = threadIdx.x;
    const float* src = out_W + ((size_t)layer * 256 + k) * 512;
    #pragma unroll
    for (int q = 0; q < 2; ++q) {
        int ee = e + q * 256;
        int P = ee & 255, half = ee >> 8;
        int by = P >> 6, pp = P & 63;
        int g = pp >> 5;
        int tcol = (pp & 31) + half * 32;
        int c = by * 128 + g * 64 + tcol;
        Wtp[((size_t)layer * 512 + c) * 256 + k] = __float2bfloat16(src[ee]);
    }
}

// ---------------------------------------------------------------------------
// 2) input projection -> Ub[b][d][l] bf16, zeroes pad
// ---------------------------------------------------------------------------
__global__ __launch_bounds__(256) void input_proj_kernel(
    const float* __restrict__ xp, const float* __restrict__ nf,
    const float* __restrict__ xf, const float* __restrict__ sa,
    const float* __restrict__ inW, const float* __restrict__ inb,
    const float* __restrict__ tb, __hip_bfloat16* __restrict__ Ub) {
    int b  = blockIdx.y;
    int l0 = blockIdx.x * 256;
    int tx = threadIdx.x;
    int l  = l0 + tx;

    __shared__ float feats[256][18];
    __shared__ float Ws[17][DM];
    __shared__ float sdot[DM];
    __shared__ float tbs[DM];
    __shared__ float sstat[SDIM];

    if (tx < SDIM) sstat[tx] = sa[b * SDIM + tx];
    for (int k = 0; k < 17; ++k) Ws[k][tx] = inW[k * DM + tx];
    tbs[tx] = tb[b * DM + tx];

    bool valid = (l < LT);
    if (valid) {
        const float* src = (l < L_) ? &xp[((size_t)b * L_ + l) * DMET]
                                    : &xf[((size_t)b * (H_ - 1) + (l - L_)) * DMET];
        #pragma unroll
        for (int k = 0; k < DMET; ++k) feats[tx][k] = src[k];
        feats[tx][16] = (l >= L_ - 1) ? nf[b * H_ + (l - (L_ - 1))] : 0.0f;
    }
    __syncthreads();

    float sd = 0.0f;
    for (int k = 0; k < SDIM; ++k)
        sd = fmaf(sstat[k], inW[(17 + k) * DM + tx], sd);
    sdot[tx] = sd;
    __syncthreads();

    if (l >= LTR) return;
    size_t baseb = ((size_t)b * DM) * LTR + l;
    if (!valid) {
        __hip_bfloat16 z = __float2bfloat16(0.0f);
        for (int d = 0; d < DM; ++d) Ub[baseb + (size_t)d * LTR] = z;
        return;
    }
    bool cond = (l >= L_ - 1);
    for (int d = 0; d < DM; ++d) {
        float acc = inb[d] + sdot[d] + (cond ? tbs[d] : 0.0f);
        #pragma unroll
        for (int k = 0; k < 17; ++k)
            acc = fmaf(feats[tx][k], Ws[k][d], acc);
        Ub[baseb + (size_t)d * LTR] = __float2bfloat16(acc);
    }
}

// ---------------------------------------------------------------------------
// 3a) per-layer per-channel matrix prep with BN folding + stats finalize
// ---------------------------------------------------------------------------
__global__ __launch_bounds__(256) void prep_kernel(
    const float* __restrict__ log_dt,
    const float* __restrict__ A_re, const float* __restrict__ A_im,
    const float* __restrict__ C_re, const float* __restrict__ C_im,
    const float* __restrict__ Dp,
    const float* __restrict__ gamma, const float* __restrict__ beta,
    float* __restrict__ stats, float* __restrict__ scsh,
    __hip_bfloat16* __restrict__ Abig, __hip_bfloat16* __restrict__ SA,
    float* __restrict__ Rsh, float* __restrict__ T1sh, int layer) {
    int d = blockIdx.x;
    int t = threadIdx.x;
    __shared__ float sAr[64], sAi[64], sCkr[64], sCki[64];
    __shared__ float kap[TCH];
    __shared__ float csum[TCH];
    __shared__ float s_sc, s_sh;

    if (t == 0) {
        float sc, sh;
        if (layer == 0) { sc = 1.0f; sh = 0.0f; }
        else {
            float s = stats[d], q = stats[DM + d];
            float mean = s * (1.0f / NTOT);
            float var  = q * (1.0f / NTOT) - mean * mean;
            sc = rsqrtf(var + 1e-5f) * gamma[(layer - 1) * DM + d];
            sh = beta[(layer - 1) * DM + d] - mean * sc;
        }
        s_sc = sc; s_sh = sh;
        scsh[d] = sc; scsh[DM + d] = sh;
        stats[d] = 0.0f; stats[DM + d] = 0.0f;
    }
    __syncthreads();
    float sc = s_sc, sh = s_sh;

    float dt = expf(log_dt[layer * DM + d]);
    float Dd = Dp[layer * DM + d];
    if (t < 64) {
        size_t ab = ((size_t)layer * DM + d) * DS + t;
        float Ar = A_re[ab], Ai = A_im[ab], Cr = C_re[ab], Ci = C_im[ab];
        float ar = dt * Ar, ai = dt * Ai;
        float e = expf(ar);
        float wre = e * cosf(ai), wim = e * sinf(ai);
        float mr = wre - 1.0f, mi = wim;
        float den = 1.0f / (Ar * Ar + Ai * Ai);
        float qr = (mr * Ar + mi * Ai) * den, qi = (mi * Ar - mr * Ai) * den;
        sCkr[t] = Cr * qr - Ci * qi;
        sCki[t] = Cr * qi + Ci * qr;
        sAr[t] = ar;
        sAi[t] = ai;
        float s2 = sinf(0.5f * ai);
        float dr = fmaf(expm1f(ar), cosf(ai), -2.0f * s2 * s2);
        float di = e * sinf(ai);
        float a128 = 128.0f * ar, b128 = 128.0f * ai;
        float s2b = sinf(0.5f * b128);
        float nr = fmaf(expm1f(a128), cosf(b128), -2.0f * s2b * s2b);
        float ni = expf(a128) * sinf(b128);
        float dd2 = 1.0f / (dr * dr + di * di);
        float gr = (nr * dr + ni * di) * dd2;
        float gi = (ni * dr - nr * di) * dd2;
        Rsh[(size_t)d * 128 + t]      = sh * gr;
        Rsh[(size_t)d * 128 + 64 + t] = sh * gi;
    }
    __syncthreads();

    {
        int delta = t >> 1, half = t & 1;
        float fd = (float)delta;
        float p = 0.0f;
        #pragma unroll 8
        for (int n = half * 32; n < half * 32 + 32; ++n) {
            float er = fexp_(fd * sAr[n]);
            float ph = fd * sAi[n];
            p += er * (sCkr[n] * fcos_(ph) - sCki[n] * fsin_(ph));
        }
        p += __shfl_xor(p, 1);
        if (half == 0) kap[delta] = 2.0f * p + (delta == 0 ? Dd : 0.0f);
    }
    __syncthreads();

    if (t < 128) csum[t] = kap[t];
    __syncthreads();
    for (int off = 1; off < 128; off <<= 1) {
        float v = 0.0f;
        if (t >= off && t < 128) v = csum[t - off];
        __syncthreads();
        if (t < 128) csum[t] += v;
        __syncthreads();
    }
    if (t < 128) T1sh[(size_t)d * 128 + t] = sh * csum[t];

    __hip_bfloat16* Ad = Abig + (size_t)d * TCH * 256;
    for (int idx = t; idx < TCH * TCH; idx += 256) {
        int i = idx >> 7, m = idx & 127;
        Ad[(size_t)i * 256 + m] = __float2bfloat16(m <= i ? sc * kap[i - m] : 0.0f);
    }
    for (int idx = t; idx < TCH * 64; idx += 256) {
        int i = idx >> 6, n = idx & 63;
        float fp = (float)(i + 1);
        float er = fexp_(fp * sAr[n]);
        float ph = fp * sAi[n];
        float c = fcos_(ph), s = fsin_(ph);
        float vr = er * (sCkr[n] * c - sCki[n] * s);
        float vi = er * (sCkr[n] * s + sCki[n] * c);
        Ad[(size_t)i * 256 + 128 + n] = __float2bfloat16(2.0f * vr);
        Ad[(size_t)i * 256 + 192 + n] = __float2bfloat16(-2.0f * vi);
    }
    __hip_bfloat16* Sd = SA + (size_t)d * TCH * TCH;
    for (int idx = t; idx < 64 * TCH; idx += 256) {
        int n = idx >> 7, m = idx & 127;
        float fp = (float)(127 - m);
        float er = sc * fexp_(fp * sAr[n]);
        float ph = fp * sAi[n];
        Sd[(size_t)n * 128 + m]        = __float2bfloat16(er * fcos_(ph));
        Sd[(size_t)(64 + n) * 128 + m] = __float2bfloat16(er * fsin_(ph));
    }
}

// ---------------------------------------------------------------------------
// 3b) S-GEMM, 3 tiles per block, rotating 3-region LDS pipeline. (R5)
// ---------------------------------------------------------------------------
__global__ __launch_bounds__(256) void sgemm_kernel(
    const __hip_bfloat16* __restrict__ Ub, const __hip_bfloat16* __restrict__ SA,
    const float* __restrict__ Rsh, __hip_bfloat16* __restrict__ S) {
    int id = blockIdx.x;               // 768 blocks
    int xcd = id & 7, j = id >> 3;     // j in [0,96)
    int dj = (j * 21846) >> 16;        // j/3
    int d = xcd * 32 + dj;
    int g = j - dj * 3;                // cb group: cb = 3g + t
    int tid = threadIdx.x, wave = tid >> 6, lane = tid & 63;
    int lm = lane & 15, quad = lane >> 4;
    const __hip_bfloat16* SAd = SA + (size_t)d * TCH * TCH;

    __shared__ short Bs[12288];        // 24 KB: 3 regions x 8 KB

    short8 a0r[4], a1r[4];
    #pragma unroll
    for (int kk = 0; kk < 4; ++kk) {
        a0r[kk] = *(const short8*)(SAd + (size_t)(wave * 32 + lm) * TCH + kk * 32 + quad * 8);
        a1r[kk] = *(const short8*)(SAd + (size_t)(wave * 32 + 16 + lm) * TCH + kk * 32 + quad * 8);
    }

    int ntS = (tid >> 6) & 3, qS = (tid >> 4) & 3, ccS = tid & 15;
    const __hip_bfloat16* srcB[3];
    #pragma unroll
    for (int t = 0; t < 3; ++t) {
        int col = (3 * g + t) * 64 + ntS * 16 + ccS;
        int colc = col < COLS ? col : COLS - 1;
        int bh = (colc * 241) >> 12;
        int c = colc - bh * 17;
        srcB[t] = Ub + ((size_t)bh * DM + d) * LTR + (size_t)c * TCH + qS * 8;
    }

    float4 rs0 = *(const float4*)(Rsh + (size_t)d * 128 + wave * 32 + quad * 4);
    float4 rs1 = *(const float4*)(Rsh + (size_t)d * 128 + wave * 32 + 16 + quad * 4);

    floatx4 acc[2][4];
    floatx4 zf = {0.f, 0.f, 0.f, 0.f};
    #pragma unroll
    for (int mi = 0; mi < 2; ++mi)
        #pragma unroll
        for (int nt = 0; nt < 4; ++nt) acc[mi][nt] = zf;

#define SG_STAGE(t_, kk0_, off_)                                              \
    {                                                                         \
        glds16(srcB[t_] + (kk0_) * 32,     (char*)Bs + (off_) + tid * 16);    \
        glds16(srcB[t_] + (kk0_ + 1) * 32, (char*)Bs + (off_) + 4096 + tid * 16); \
    }
#define SG_COMP(off_, kkA_)                                                   \
    {                                                                         \
        const short* bb_ = (const short*)((const char*)Bs + (off_));          \
        _Pragma("unroll")                                                     \
        for (int kk_ = 0; kk_ < 2; ++kk_) {                                   \
            _Pragma("unroll")                                                 \
            for (int nt_ = 0; nt_ < 4; ++nt_) {                               \
                short8 bv = *(const short8*)(bb_ + kk_ * 2048 + nt_ * 512 + lane * 8); \
                acc[0][nt_] = __builtin_amdgcn_mfma_f32_16x16x32_bf16(        \
                    a0r[(kkA_) + kk_], bv, acc[0][nt_], 0, 0, 0);             \
                acc[1][nt_] = __builtin_amdgcn_mfma_f32_16x16x32_bf16(        \
                    a1r[(kkA_) + kk_], bv, acc[1][nt_], 0, 0, 0);             \
            }                                                                 \
        }                                                                     \
    }
#define SG_EPI(cb_)                                                           \
    _Pragma("unroll")                                                         \
    for (int mi = 0; mi < 2; ++mi) {                                          \
        int row = wave * 32 + mi * 16 + quad * 4;                             \
        float4 rs = mi ? rs1 : rs0;                                           \
        _Pragma("unroll")                                                     \
        for (int nt_ = 0; nt_ < 4; ++nt_) {                                   \
            int col = (cb_) * 64 + nt_ * 16 + lm;                             \
            if (col < COLS) {                                                 \
                short4v o;                                                    \
                o[0] = bfs(acc[mi][nt_][0] + rs.x);                           \
                o[1] = bfs(acc[mi][nt_][1] + rs.y);                           \
                o[2] = bfs(acc[mi][nt_][2] + rs.z);                           \
                o[3] = bfs(acc[mi][nt_][3] + rs.w);                           \
                *(short4v*)(S + ((size_t)d * COLS + col) * TCH + row) = o;    \
            }                                                                 \
            acc[mi][nt_] = zf;                                                \
        }                                                                     \
    }

    SG_STAGE(0, 0, 0);
    SG_STAGE(0, 2, 8192);
    SG_STAGE(1, 0, 16384);
    BARV(4);
    SG_COMP(0, 0);
    BARV(2);
    SG_STAGE(1, 2, 0);
    SG_COMP(8192, 2);
    BARV(2);
    SG_STAGE(2, 0, 8192);
    SG_EPI(3 * g + 0);
    BARV(4);
    SG_COMP(16384, 0);
    BARV(2);
    SG_STAGE(2, 2, 16384);
    SG_COMP(0, 2);
    SG_EPI(3 * g + 1);
    BARV(2);
    SG_COMP(8192, 0);
    BARV(0);
    SG_COMP(16384, 2);
    SG_EPI(3 * g + 2);

#undef SG_STAGE
#undef SG_COMP
#undef SG_EPI
}

// ---------------------------------------------------------------------------
// 3c) carry scan over chunks (in place), loads prefetched up front
// ---------------------------------------------------------------------------
__global__ __launch_bounds__(64) void carry_kernel(
    __hip_bfloat16* __restrict__ SX,
    const float* __restrict__ log_dt,
    const float* __restrict__ A_re, const float* __restrict__ A_im,
    int layer) {
    int d = blockIdx.x, b = blockIdx.y;
    int n = threadIdx.x;
    float dt = expf(log_dt[layer * DM + d]);
    size_t ab = ((size_t)layer * DM + d) * DS + n;
    float Ar = A_re[ab], Ai = A_im[ab];
    float e = expf(dt * Ar);
    float wre = e * cosf(dt * Ai), wim = e * sinf(dt * Ai);
    #pragma unroll
    for (int t = 0; t < 7; ++t) {
        float r = wre * wre - wim * wim;
        wim = 2.0f * wre * wim; wre = r;
    }
    size_t base = ((size_t)d * COLS + (size_t)b * NC) * TCH + n;
    float sre[NC], sim[NC];
    #pragma unroll
    for (int c = 0; c < NC; ++c) {
        sre[c] = __bfloat162float(SX[base + (size_t)c * TCH]);
        sim[c] = __bfloat162float(SX[base + (size_t)c * TCH + 64]);
    }
    float xr = 0.0f, xi = 0.0f;
    #pragma unroll
    for (int c = 0; c < NC; ++c) {
        SX[base + (size_t)c * TCH]      = __float2bfloat16(xr);
        SX[base + (size_t)c * TCH + 64] = __float2bfloat16(xi);
        float nr = wre * xr - wim * xi + sre[c];
        xi = wre * xi + wim * xr + sim[c];
        xr = nr;
    }
}

// ---------------------------------------------------------------------------
// 3d) main chunk GEMM, 3 tiles per block, rotating 3x16KB LDS pipeline. (R5)
// ---------------------------------------------------------------------------
__global__ __launch_bounds__(256) void mainscan_kernel(
    const __hip_bfloat16* __restrict__ Ub, const __hip_bfloat16* __restrict__ X,
    const __hip_bfloat16* __restrict__ Abig, const float* __restrict__ T1sh,
    __hip_bfloat16* __restrict__ Ybt) {
    int id = blockIdx.x;               // 768 blocks
    int xcd = id & 7, j = id >> 3;     // j in [0,96)
    int dj = (j * 21846) >> 16;        // j/3
    int d = xcd * 32 + dj;
    int g = j - dj * 3;                // cb = 3g + t
    int tid = threadIdx.x, wave = tid >> 6, lane = tid & 63;
    int lm = lane & 15, quad = lane >> 4;
    const __hip_bfloat16* Ad = Abig + (size_t)d * TCH * 256;

    __shared__ short Bs[24576];        // 48 KB: 3 regions x 16 KB

    short8 a0r[8], a1r[8];
    #pragma unroll
    for (int kk = 0; kk < 8; ++kk) {
        a0r[kk] = *(const short8*)(Ad + (size_t)(wave * 32 + lm) * 256 + kk * 32 + quad * 8);
        a1r[kk] = *(const short8*)(Ad + (size_t)(wave * 32 + 16 + lm) * 256 + kk * 32 + quad * 8);
    }

    int ntS = (tid >> 6) & 3, qS = (tid >> 4) & 3, ccS = tid & 15;
    const __hip_bfloat16* srcU[3];
    const __hip_bfloat16* srcX[3];
    #pragma unroll
    for (int t = 0; t < 3; ++t) {
        int col = (3 * g + t) * 64 + ntS * 16 + ccS;
        int colc = col < COLS ? col : COLS - 1;
        int bh = (colc * 241) >> 12;
        int c = colc - bh * 17;
        srcU[t] = Ub + ((size_t)bh * DM + d) * LTR + (size_t)c * TCH + qS * 8;
        srcX[t] = X + ((size_t)d * COLS + colc) * TCH + qS * 8;
    }

    float4 t1a = *(const float4*)(T1sh + (size_t)d * 128 + wave * 32 + quad * 4);
    float4 t1b = *(const float4*)(T1sh + (size_t)d * 128 + wave * 32 + 16 + quad * 4);

    floatx4 acc[2][4];
    floatx4 zf = {0.f, 0.f, 0.f, 0.f};
    #pragma unroll
    for (int mi = 0; mi < 2; ++mi)
        #pragma unroll
        for (int nt = 0; nt < 4; ++nt) acc[mi][nt] = zf;

#define MS_STAGE_LO(t_, off_)                                                 \
    {                                                                         \
        _Pragma("unroll")                                                     \
        for (int k_ = 0; k_ < 4; ++k_)                                        \
            glds16(srcU[t_] + k_ * 32,                                        \
                   (char*)Bs + (off_) + k_ * 4096 + tid * 16);                \
    }
#define MS_STAGE_HI(t_, off_)                                                 \
    {                                                                         \
        _Pragma("unroll")                                                     \
        for (int k_ = 0; k_ < 4; ++k_)                                        \
            glds16(srcX[t_] + k_ * 32,                                        \
                   (char*)Bs + (off_) + k_ * 4096 + tid * 16);                \
    }
#define MS_COMP(off_, kkA_)                                                   \
    {                                                                         \
        const short* bb_ = (const short*)((const char*)Bs + (off_));          \
        _Pragma("unroll")                                                     \
        for (int kk_ = 0; kk_ < 4; ++kk_) {                                   \
            _Pragma("unroll")                                                 \
            for (int nt_ = 0; nt_ < 4; ++nt_) {                               \
                short8 bv = *(const short8*)(bb_ + kk_ * 2048 + nt_ * 512 + lane * 8); \
                acc[0][nt_] = __builtin_amdgcn_mfma_f32_16x16x32_bf16(        \
                    a0r[(kkA_) + kk_], bv, acc[0][nt_], 0, 0, 0);             \
                acc[1][nt_] = __builtin_amdgcn_mfma_f32_16x16x32_bf16(        \
                    a1r[(kkA_) + kk_], bv, acc[1][nt_], 0, 0, 0);             \
            }                                                                 \
        }                                                                     \
    }
#define MS_EPI(cb_)                                                           \
    _Pragma("unroll")                                                         \
    for (int mi = 0; mi < 2; ++mi) {                                          \
        int row0 = wave * 32 + mi * 16 + quad * 4;                            \
        float4 t1 = mi ? t1b : t1a;                                           \
        _Pragma("unroll")                                                     \
        for (int nt_ = 0; nt_ < 4; ++nt_) {                                   \
            int col = (cb_) * 64 + nt_ * 16 + lm;                             \
            if (col < COLS) {                                                 \
                int bh = (col * 241) >> 12;                                   \
                int c = col - bh * 17;                                        \
                int l0 = c * TCH + row0;                                      \
                float g0 = gelu_tanh(acc[mi][nt_][0] + t1.x);                 \
                float g1 = gelu_tanh(acc[mi][nt_][1] + t1.y);                 \
                float g2 = gelu_tanh(acc[mi][nt_][2] + t1.z);                 \
                float g3 = gelu_tanh(acc[mi][nt_][3] + t1.w);                 \
                __hip_bfloat16* dst = Ybt + ((size_t)bh * DM + d) * LTR + l0; \
                if (l0 + 3 < LT) {                                            \
                    short4v o;                                                \
                    o[0] = bfs(g0); o[1] = bfs(g1);                           \
                    o[2] = bfs(g2); o[3] = bfs(g3);                           \
                    *(short4v*)dst = o;                                       \
                } else {                                                      \
                    if (l0 + 0 < LT) dst[0] = __float2bfloat16(g0);           \
                    if (l0 + 1 < LT) dst[1] = __float2bfloat16(g1);           \
                    if (l0 + 2 < LT) dst[2] = __float2bfloat16(g2);           \
                    if (l0 + 3 < LT) dst[3] = __float2bfloat16(g3);           \
                }                                                             \
            }                                                                 \
            acc[mi][nt_] = zf;                                                \
        }                                                                     \
    }

    MS_STAGE_LO(0, 0);
    MS_STAGE_HI(0, 16384);
    MS_STAGE_LO(1, 32768);
    BARV(8);
    MS_COMP(0, 0);
    BARV(4);
    MS_STAGE_HI(1, 0);
    MS_COMP(16384, 4);
    BARV(4);
    MS_STAGE_LO(2, 16384);
    MS_EPI(3 * g + 0);
    BARV(8);
    MS_COMP(32768, 0);
    BARV(4);
    MS_STAGE_HI(2, 32768);
    MS_COMP(0, 4);
    MS_EPI(3 * g + 1);
    BARV(4);
    MS_COMP(16384, 0);
    BARV(0);
    MS_COMP(32768, 4);
    MS_EPI(3 * g + 2);

#undef MS_STAGE_LO
#undef MS_STAGE_HI
#undef MS_COMP
#undef MS_EPI
}

// ---------------------------------------------------------------------------
// 4) GEMM + GLU + residual + BN stats.  by-fused, LDS-B ELIMINATED:
//    A (transposed Ybt tile) staged once into 64 KB swizzled LDS (write-once
//    disjoint regions -> lgkm-only barriers, 8 total); B fragments loaded
//    DIRECTLY global->regs (Wtp is L2-resident), double-buffered 2 substeps
//    deep.  by=1..3 run with ZERO barriers.  LDS 64 KB -> 2 blocks/CU.
// ---------------------------------------------------------------------------
__global__ __launch_bounds__(256, 2) void gemm_glu_mfma_kernel(
    const __hip_bfloat16* __restrict__ Ybt, __hip_bfloat16* __restrict__ Ub,
    const __hip_bfloat16* __restrict__ Wtp, const float* __restrict__ out_b,
    const float* __restrict__ scsh, float* __restrict__ stats, int layer) {
    int sub = blockIdx.x;              // 544 blocks
    int bq = (sub * 3856) >> 16;       // sub/17
    int bx = sub - bq * 17;
    int b = bq;
    int tid = threadIdx.x;
    int wave = tid >> 6, lane = tid & 63;
    int lm = lane & 15, quad = lane >> 4;
    int l0 = bx * 128;

    __shared__ short lds[32768];       // 64 KB: resident A only

    // ---- A-staging mapping: thread = (kp in [0,16), l8 in [0,16)) ----
    int kp = tid >> 4;
    int l8 = tid & 15;
    const __hip_bfloat16* srcA = Ybt + ((size_t)b * DM + 2 * kp) * LTR + l0 + l8 * 8;
    int pbA[8], lbA[8];
    {
        int kg4 = kp >> 2;
        #pragma unroll
        for (int jj = 0; jj < 8; ++jj) {
            int lloc = l8 * 8 + jj;
            pbA[jj] = kg4 + lloc + (lloc >> 3);
            lbA[jj] = lloc * 256 + (kp & 3) * 2;
        }
    }
    // ---- fragment read precompute (A) ----
    int rA_[4], abA_[4];
    #pragma unroll
    for (int mi = 0; mi < 4; ++mi) {
        int r = (wave >> 1) * 64 + mi * 16 + lm;
        rA_[mi] = r * 256;
        abA_[mi] = quad + r + (r >> 3);
    }
    // ---- B direct-load base: frag(ni,S,by) = srcBF + by*32768 + ni*4096 + S*32
    const __hip_bfloat16* srcBF = Wtp + (size_t)layer * 512 * 256
                                + (size_t)((wave & 1) * 64 + lm) * 256 + quad * 8;

    floatx4 acc[4][4];
    floatx4 zf = {0.f, 0.f, 0.f, 0.f};
    #pragma unroll
    for (int mi = 0; mi < 4; ++mi)
        #pragma unroll
        for (int ni = 0; ni < 4; ++ni) acc[mi][ni] = zf;

    const float* bl = out_b + layer * 512;
    int lwq = l0 + (wave >> 1) * 64;

#define LOAD_A(S, G0, G1)                                                     \
    {                                                                         \
        const __hip_bfloat16* pa_ = srcA + (size_t)(S) * 32 * LTR;            \
        G0 = *(const short8*)pa_;                                             \
        G1 = *(const short8*)(pa_ + LTR);                                     \
    }
#define WRITE_A(S, G0, G1)                                                    \
    {                                                                         \
        _Pragma("unroll")                                                     \
        for (int j_ = 0; j_ < 8; ++j_) {                                      \
            unsigned pk_ = (unsigned)(unsigned short)G0[j_] |                 \
                           ((unsigned)(unsigned short)G1[j_] << 16);          \
            int off_ = lbA[j_] + (((S) * 4 + pbA[j_]) & 31) * 8;              \
            *(unsigned*)(lds + off_) = pk_;                                   \
        }                                                                     \
    }
#define LOADB(S, BY, F)                                                       \
    {                                                                         \
        const __hip_bfloat16* pb_ = srcBF + (size_t)(BY) * 32768 + (S) * 32;  \
        _Pragma("unroll")                                                     \
        for (int ni_ = 0; ni_ < 4; ++ni_)                                     \
            F[ni_] = *(const short8*)(pb_ + ni_ * 4096);                      \
    }
#define COMPUTEB(S, F)                                                        \
    {                                                                         \
        short8 af_[4];                                                        \
        _Pragma("unroll")                                                     \
        for (int mi_ = 0; mi_ < 4; ++mi_)                                     \
            af_[mi_] = *(const short8*)(lds + rA_[mi_] +                      \
                         (((S) * 4 + abA_[mi_]) & 31) * 8);                   \
        _Pragma("unroll")                                                     \
        for (int mi_ = 0; mi_ < 4; ++mi_)                                     \
            _Pragma("unroll")                                                 \
            for (int ni_ = 0; ni_ < 4; ++ni_)                                 \
                acc[mi_][ni_] = __builtin_amdgcn_mfma_f32_16x16x32_bf16(      \
                    af_[mi_], F[ni_], acc[mi_][ni_], 0, 0, 0);                \
    }
#define EPILOGUE(BY)                                                          \
    {                                                                         \
        int Pbase_ = (BY) * 64 + (wave & 1) * 32;                             \
        _Pragma("unroll")                                                     \
        for (int ni = 0; ni < 2; ++ni) {                                      \
            int P = Pbase_ + ni * 16 + lm;                                    \
            float bz1 = bl[P], bz2 = bl[256 + P];                             \
            float scP = scsh[P], shP = scsh[DM + P];                          \
            __hip_bfloat16* ubrow = Ub + ((size_t)b * DM + P) * LTR;          \
            float sp = 0.f, sq = 0.f;                                         \
            _Pragma("unroll")                                                 \
            for (int mi = 0; mi < 4; ++mi) {                                  \
                int l0q = lwq + mi * 16 + quad * 4;                           \
                floatx4 z1 = acc[mi][ni];                                     \
                floatx4 z2 = acc[mi][ni + 2];                                 \
                acc[mi][ni] = zf; acc[mi][ni + 2] = zf;                       \
                if (l0q >= LT) continue;                                      \
                if (l0q + 4 <= LT) {                                          \
                    short4v uv = *(const short4v*)(ubrow + l0q);              \
                    float h0 = fmaf(scP, sbf(uv[0]), shP) +                   \
                               (z1[0] + bz1) * sigmoidf_(z2[0] + bz2);        \
                    float h1 = fmaf(scP, sbf(uv[1]), shP) +                   \
                               (z1[1] + bz1) * sigmoidf_(z2[1] + bz2);        \
                    float h2 = fmaf(scP, sbf(uv[2]), shP) +                   \
                               (z1[2] + bz1) * sigmoidf_(z2[2] + bz2);        \
                    float h3 = fmaf(scP, sbf(uv[3]), shP) +                   \
                               (z1[3] + bz1) * sigmoidf_(z2[3] + bz2);        \
                    short4v ov;                                               \
                    ov[0] = bfs(h0); ov[1] = bfs(h1);                         \
                    ov[2] = bfs(h2); ov[3] = bfs(h3);                         \
                    *(short4v*)(ubrow + l0q) = ov;                            \
                    sp += (h0 + h1) + (h2 + h3);                              \
                    sq += (h0 * h0 + h1 * h1) + (h2 * h2 + h3 * h3);          \
                } else {                                                      \
                    _Pragma("unroll")                                         \
                    for (int r = 0; r < 4; ++r) {                             \
                        int l = l0q + r;                                      \
                        if (l < LT) {                                         \
                            float uvv = __bfloat162float(ubrow[l]);           \
                            float hh = fmaf(scP, uvv, shP) +                  \
                                (z1[r] + bz1) * sigmoidf_(z2[r] + bz2);       \
                            ubrow[l] = __float2bfloat16(hh);                  \
                            sp += hh; sq += hh * hh;                          \
                        }                                                     \
                    }                                                         \
                }                                                             \
            }                                                                 \
            sp += __shfl_xor(sp, 16); sp += __shfl_xor(sp, 32);               \
            sq += __shfl_xor(sq, 16); sq += __shfl_xor(sq, 32);               \
            if (quad == 0) {                                                  \
                atomicAdd(&stats[P], sp);                                     \
                atomicAdd(&stats[DM + P], sq);                                \
            }                                                                 \
        }                                                                     \
    }

    short8 gE0, gE1, gO0, gO1;
    short8 bf0[4], bf1[4];

    // ---- phase 1: by=0 compute + resident-A staging (8 lgkm barriers) ----
    LOAD_A(0, gE0, gE1);
    LOADB(0, 0, bf0);
    WRITE_A(0, gE0, gE1);
    LOAD_A(1, gO0, gO1);
    LOADB(1, 0, bf1);
    BARL;                               // A(0) visible
    COMPUTEB(0, bf0); WRITE_A(1, gO0, gO1); LOAD_A(2, gE0, gE1); LOADB(2, 0, bf0); BARL;
    COMPUTEB(1, bf1); WRITE_A(2, gE0, gE1); LOAD_A(3, gO0, gO1); LOADB(3, 0, bf1); BARL;
    COMPUTEB(2, bf0); WRITE_A(3, gO0, gO1); LOAD_A(4, gE0, gE1); LOADB(4, 0, bf0); BARL;
    COMPUTEB(3, bf1); WRITE_A(4, gE0, gE1); LOAD_A(5, gO0, gO1); LOADB(5, 0, bf1); BARL;
    COMPUTEB(4, bf0); WRITE_A(5, gO0, gO1); LOAD_A(6, gE0, gE1); LOADB(6, 0, bf0); BARL;
    COMPUTEB(5, bf1); WRITE_A(6, gE0, gE1); LOAD_A(7, gO0, gO1); LOADB(7, 0, bf1); BARL;
    COMPUTEB(6, bf0); WRITE_A(7, gO0, gO1); LOADB(0, 1, bf0); BARL;
    COMPUTEB(7, bf1); LOADB(1, 1, bf1);
    EPILOGUE(0);

    // ---- phase 2: by=1..3, zero barriers, B regs double-buffered ----
    // by = 1
    COMPUTEB(0, bf0); LOADB(2, 1, bf0);
    COMPUTEB(1, bf1); LOADB(3, 1, bf1);
    COMPUTEB(2, bf0); LOADB(4, 1, bf0);
    COMPUTEB(3, bf1); LOADB(5, 1, bf1);
    COMPUTEB(4, bf0); LOADB(6, 1, bf0);
    COMPUTEB(5, bf1); LOADB(7, 1, bf1);
    COMPUTEB(6, bf0); LOADB(0, 2, bf0);
    COMPUTEB(7, bf1); LOADB(1, 2, bf1);
    EPILOGUE(1);
    // by = 2
    COMPUTEB(0, bf0); LOADB(2, 2, bf0);
    COMPUTEB(1, bf1); LOADB(3, 2, bf1);
    COMPUTEB(2, bf0); LOADB(4, 2, bf0);
    COMPUTEB(3, bf1); LOADB(5, 2, bf1);
    COMPUTEB(4, bf0); LOADB(6, 2, bf0);
    COMPUTEB(5, bf1); LOADB(7, 2, bf1);
    COMPUTEB(6, bf0); LOADB(0, 3, bf0);
    COMPUTEB(7, bf1); LOADB(1, 3, bf1);
    EPILOGUE(2);
    // by = 3
    COMPUTEB(0, bf0); LOADB(2, 3, bf0);
    COMPUTEB(1, bf1); LOADB(3, 3, bf1);
    COMPUTEB(2, bf0); LOADB(4, 3, bf0);
    COMPUTEB(3, bf1); LOADB(5, 3, bf1);
    COMPUTEB(4, bf0); LOADB(6, 3, bf0);
    COMPUTEB(5, bf1); LOADB(7, 3, bf1);
    COMPUTEB(6, bf0);
    COMPUTEB(7, bf1);
    EPILOGUE(3);

#undef LOAD_A
#undef WRITE_A
#undef LOADB
#undef COMPUTEB
#undef EPILOGUE
}

// ---------------------------------------------------------------------------
// 5) final stats -> (sc, sh) for head
// ---------------------------------------------------------------------------
__global__ __launch_bounds__(256) void statsfin_kernel(
    const float* __restrict__ stats,
    const float* __restrict__ gamma, const float* __restrict__ beta,
    float* __restrict__ scsh, int layer) {
    int d = threadIdx.x;
    float s = stats[d], q = stats[DM + d];
    float mean = s * (1.0f / NTOT);
    float var  = q * (1.0f / NTOT) - mean * mean;
    float sc = rsqrtf(var + 1e-5f) * gamma[layer * DM + d];
    scsh[d] = sc;
    scsh[DM + d] = beta[layer * DM + d] - mean * sc;
}

// ---------------------------------------------------------------------------
// 6) head
// ---------------------------------------------------------------------------
__global__ __launch_bounds__(128) void head_kernel(
    const __hip_bfloat16* __restrict__ Ub, const float* __restrict__ scsh,
    const float* __restrict__ W1, const float* __restrict__ b1,
    const float* __restrict__ W2, const float* __restrict__ b2,
    float* __restrict__ out) {
    int hh = blockIdx.x;
    int b  = blockIdx.y;
    int j  = threadIdx.x;
    int l  = (L_ - 1) + hh;
    const __hip_bfloat16* urow = Ub + ((size_t)b * DM) * LTR + l;
    float a = b1[j];
    for (int k = 0; k < DM; ++k) {
        float hn = fmaf(scsh[k], __bfloat162float(urow[(size_t)k * LTR]), scsh[DM + k]);
        a = fmaf(hn, W1[k * 128 + j], a);
    }
    float hs = a * sigmoidf_(a);
    float v = hs * W2[j];
    v += __shfl_xor(v, 1);
    v += __shfl_xor(v, 2);
    v += __shfl_xor(v, 4);
    v += __shfl_xor(v, 8);
    v += __shfl_xor(v, 16);
    v += __shfl_xor(v, 32);
    __shared__ float partial[2];
    if ((j & 63) == 0) partial[j >> 6] = v;
    __syncthreads();
    if (j == 0) out[b * H_ + hh] = partial[0] + partial[1] + b2[0];
}

// ---------------------------------------------------------------------------
extern "C" void kernel_launch(void* const* d_in, const int* in_sizes, int n_in,
                              void* d_out, int out_size, void* d_ws, size_t ws_size,
                              hipStream_t stream) {
    (void)in_sizes; (void)n_in; (void)out_size; (void)ws_size;
    const float* x_past      = (const float*)d_in[0];
    const float* noisy       = (const float*)d_in[1];
    const float* t_in        = (const float*)d_in[2];
    const float* x_future    = (const float*)d_in[3];
    const float* static_attr = (const float*)d_in[4];
    const float* freqs       = (const float*)d_in[5];
    const float* phases      = (const float*)d_in[6];
    const float* in_W        = (const float*)d_in[7];
    const float* in_b        = (const float*)d_in[8];
    const float* tm_W1       = (const float*)d_in[9];
    const float* tm_b1       = (const float*)d_in[10];
    const float* tm_W2       = (const float*)d_in[11];
    const float* tm_b2       = (const float*)d_in[12];
    const float* log_dt      = (const float*)d_in[13];
    const float* A_re        = (const float*)d_in[14];
    const float* A_im        = (const float*)d_in[15];
    const float* C_re        = (const float*)d_in[16];
    const float* C_im        = (const float*)d_in[17];
    const float* Dp          = (const float*)d_in[18];
    const float* out_W       = (const float*)d_in[19];
    const float* out_b       = (const float*)d_in[20];
    const float* bn_gamma    = (const float*)d_in[21];
    const float* bn_beta     = (const float*)d_in[22];
    const float* head_W1     = (const float*)d_in[23];
    const float* head_b1     = (const float*)d_in[24];
    const float* head_W2     = (const float*)d_in[25];
    const float* head_b2     = (const float*)d_in[26];

    char* ws = (char*)d_ws;
    const size_t UB_OFF = 1u << 20;
    const size_t UB_BYT = (size_t)B_ * DM * LTR * 2;
    const size_t R1_OFF = UB_OFF + UB_BYT;
    const size_t RB     = (size_t)256 * COLS * TCH * 2;
    const size_t R2_OFF = R1_OFF + RB;
    const size_t AB_OFF = R2_OFF + RB;
    const size_t AB_BYT = (size_t)256 * TCH * 256 * 2;
    const size_t SA_OFF = AB_OFF + AB_BYT;
    const size_t SA_BYT = (size_t)256 * TCH * TCH * 2;
    const size_t WT_OFF = SA_OFF + SA_BYT;

    float*          tb    = (float*)(ws);
    float*          stats = (float*)(ws + (64 << 10));
    float*          scsh  = (float*)(ws + (96 << 10));
    float*          Rsh   = (float*)(ws + (128 << 10));
    float*          T1sh  = (float*)(ws + (256 << 10));
    __hip_bfloat16* Ub    = (__hip_bfloat16*)(ws + UB_OFF);
    __hip_bfloat16* R1    = (__hip_bfloat16*)(ws + R1_OFF);
    __hip_bfloat16* Ybt   = (__hip_bfloat16*)(ws + R2_OFF);
    __hip_bfloat16* Abig  = (__hip_bfloat16*)(ws + AB_OFF);
    __hip_bfloat16* SA    = (__hip_bfloat16*)(ws + SA_OFF);
    __hip_bfloat16* Wtp   = (__hip_bfloat16*)(ws + WT_OFF);

    time_mlp_kernel<<<dim3(B_), 256, 0, stream>>>(
        t_in, freqs, phases, tm_W1, tm_b1, tm_W2, tm_b2, tb);

    wt_prep_kernel<<<dim3(NL * 256), 256, 0, stream>>>(out_W, Wtp);

    input_proj_kernel<<<dim3(9, B_), 256, 0, stream>>>(
        x_past, noisy, x_future, static_attr, in_W, in_b, tb, Ub);

    for (int layer = 0; layer < NL; ++layer) {
        prep_kernel<<<dim3(256), 256, 0, stream>>>(
            log_dt, A_re, A_im, C_re, C_im, Dp, bn_gamma, bn_beta,
            stats, scsh, Abig, SA, Rsh, T1sh, layer);
        sgemm_kernel<<<dim3(768), 256, 0, stream>>>(Ub, SA, Rsh, R1);
        carry_kernel<<<dim3(256, B_), 64, 0, stream>>>(
            R1, log_dt, A_re, A_im, layer);
        mainscan_kernel<<<dim3(768), 256, 0, stream>>>(Ub, R1, Abig, T1sh, Ybt);
        gemm_glu_mfma_kernel<<<dim3(544), 256, 0, stream>>>(
            Ybt, Ub, Wtp, out_b, scsh, stats, layer);
    }

    statsfin_kernel<<<dim3(1), 256, 0, stream>>>(
        stats, bn_gamma, bn_beta, scsh, NL - 1);

    head_kernel<<<dim3(H_, B_), 128, 0, stream>>>(
        Ub, scsh, head_W1, head_b1, head_W2, head_b2, (float*)d_out);
}

// Round 8
// 777.496 us; speedup vs baseline: 1.1714x; 1.1714x over previous
//
#include <hip/hip_runtime.h>
#include <hip/hip_bf16.h>
#include <math.h>

#define B_   32
#define L_   2048
#define H_   8
#define DMET 16
#define SDIM 27
#define DM   256
#define NL   4
#define DS   64
#define TE   256
#define LT   2055          // L + H - 1
#define LTR  2176          // 17*128: padded l for Ub/Ybt
#define TCH  128           // chunk length
#define NC   17            // chunks per sequence
#define COLS 544           // B_ * NC
#define NTOT (B_ * LT)

typedef __attribute__((ext_vector_type(8))) short short8;
typedef __attribute__((ext_vector_type(4))) short short4v;
typedef __attribute__((ext_vector_type(4))) float floatx4;

// fast sigmoid: 1/(1+2^(-x*log2 e)) via v_exp_f32 + v_rcp_f32.
__device__ __forceinline__ float sigmoidf_(float x) {
    float e = __builtin_amdgcn_exp2f(-1.4426950408889634f * x);
    return __builtin_amdgcn_rcpf(1.0f + e);
}

// tanh-gelu in sigmoid form: 0.5*(1+tanh(z)) == sigmoid(2z) exactly.
__device__ __forceinline__ float gelu_tanh(float x) {
    float inner = 1.5957691216057308f * fmaf(0.044715f * x * x, x, x);
    return x * sigmoidf_(inner);
}

// hardware exp/sin/cos (revolutions, fract-reduced).
__device__ __forceinline__ float fexp_(float x) {
    return __builtin_amdgcn_exp2f(1.4426950408889634f * x);
}
__device__ __forceinline__ float fsin_(float ph) {
    float r = ph * 0.15915494309189535f;
    r = r - floorf(r);
    return __builtin_amdgcn_sinf(r);
}
__device__ __forceinline__ float fcos_(float ph) {
    float r = ph * 0.15915494309189535f;
    r = r - floorf(r);
    return __builtin_amdgcn_cosf(r);
}

__device__ __forceinline__ short bfs(float x) {
    __hip_bfloat16 h = __float2bfloat16(x);
    return *(short*)&h;
}

__device__ __forceinline__ float sbf(short s) {
    unsigned u = ((unsigned)(unsigned short)s) << 16;
    return __uint_as_float(u);
}

__device__ __forceinline__ void glds16(const void* g, void* l) {
    __builtin_amdgcn_global_load_lds(
        (const __attribute__((address_space(1))) unsigned*)g,
        (__attribute__((address_space(3))) unsigned*)l, 16, 0, 0);
}

// counted-vmcnt fence + full barrier (for glds-based kernels)
#define BARV(n) do {                                                          \
    asm volatile("s_waitcnt vmcnt(" #n ") lgkmcnt(0)" ::: "memory");          \
    __builtin_amdgcn_s_barrier();                                             \
    asm volatile("" ::: "memory");                                            \
} while (0)

// lgkm-only fence + barrier (ds visibility; vmem loads stay in flight)
#define BARL do {                                                             \
    asm volatile("s_waitcnt lgkmcnt(0)" ::: "memory");                        \
    __builtin_amdgcn_sched_barrier(0);                                        \
    __builtin_amdgcn_s_barrier();                                             \
    asm volatile("" ::: "memory");                                            \
} while (0)

// ---------------------------------------------------------------------------
// 1) time MLP
// ---------------------------------------------------------------------------
__global__ __launch_bounds__(256) void time_mlp_kernel(
    const float* __restrict__ t, const float* __restrict__ freqs,
    const float* __restrict__ phases,
    const float* __restrict__ W1, const float* __restrict__ b1,
    const float* __restrict__ W2, const float* __restrict__ b2,
    float* __restrict__ tb) {
    int b = blockIdx.x;
    int tid = threadIdx.x;
    __shared__ float f[TE];
    __shared__ float hid[2 * TE];
    float tv = t[b];
    f[tid] = cosf(fmaf(tv, freqs[tid], phases[tid])) * 1.4142135623730951f;
    __syncthreads();
    float a0 = b1[tid], a1 = b1[tid + TE];
    for (int k = 0; k < TE; ++k) {
        float fk = f[k];
        a0 = fmaf(fk, W1[k * 2 * TE + tid], a0);
        a1 = fmaf(fk, W1[k * 2 * TE + tid + TE], a1);
    }
    hid[tid]      = a0 * sigmoidf_(a0);
    hid[tid + TE] = a1 * sigmoidf_(a1);
    __syncthreads();
    float acc = b2[tid];
    for (int j = 0; j < 2 * TE; ++j)
        acc = fmaf(hid[j], W2[j * DM + tid], acc);
    tb[b * DM + tid] = acc;
}

// ---------------------------------------------------------------------------
// 1b) out_W [NL][256][512] fp32 -> Wtp bf16 [NL][512 permuted cols][256 k]
// ---------------------------------------------------------------------------
__global__ __launch_bounds__(256) void wt_prep_kernel(
    const float* __restrict__ out_W, __hip_bfloat16* __restrict__ Wtp) {
    int bid = blockIdx.x;
    int layer = bid >> 8, k = bid & 255;
    int e = threadIdx.x;
    const float* src = out_W + ((size_t)layer * 256 + k) * 512;
    #pragma unroll
    for (int q = 0; q < 2; ++q) {
        int ee = e + q * 256;
        int P = ee & 255, half = ee >> 8;
        int by = P >> 6, pp = P & 63;
        int g = pp >> 5;
        int tcol = (pp & 31) + half * 32;
        int c = by * 128 + g * 64 + tcol;
        Wtp[((size_t)layer * 512 + c) * 256 + k] = __float2bfloat16(src[ee]);
    }
}

// ---------------------------------------------------------------------------
// 2) input projection -> Ub[b][d][l] bf16, zeroes pad
// ---------------------------------------------------------------------------
__global__ __launch_bounds__(256) void input_proj_kernel(
    const float* __restrict__ xp, const float* __restrict__ nf,
    const float* __restrict__ xf, const float* __restrict__ sa,
    const float* __restrict__ inW, const float* __restrict__ inb,
    const float* __restrict__ tb, __hip_bfloat16* __restrict__ Ub) {
    int b  = blockIdx.y;
    int l0 = blockIdx.x * 256;
    int tx = threadIdx.x;
    int l  = l0 + tx;

    __shared__ float feats[256][18];
    __shared__ float Ws[17][DM];
    __shared__ float sdot[DM];
    __shared__ float tbs[DM];
    __shared__ float sstat[SDIM];

    if (tx < SDIM) sstat[tx] = sa[b * SDIM + tx];
    for (int k = 0; k < 17; ++k) Ws[k][tx] = inW[k * DM + tx];
    tbs[tx] = tb[b * DM + tx];

    bool valid = (l < LT);
    if (valid) {
        const float* src = (l < L_) ? &xp[((size_t)b * L_ + l) * DMET]
                                    : &xf[((size_t)b * (H_ - 1) + (l - L_)) * DMET];
        #pragma unroll
        for (int k = 0; k < DMET; ++k) feats[tx][k] = src[k];
        feats[tx][16] = (l >= L_ - 1) ? nf[b * H_ + (l - (L_ - 1))] : 0.0f;
    }
    __syncthreads();

    float sd = 0.0f;
    for (int k = 0; k < SDIM; ++k)
        sd = fmaf(sstat[k], inW[(17 + k) * DM + tx], sd);
    sdot[tx] = sd;
    __syncthreads();

    if (l >= LTR) return;
    size_t baseb = ((size_t)b * DM) * LTR + l;
    if (!valid) {
        __hip_bfloat16 z = __float2bfloat16(0.0f);
        for (int d = 0; d < DM; ++d) Ub[baseb + (size_t)d * LTR] = z;
        return;
    }
    bool cond = (l >= L_ - 1);
    for (int d = 0; d < DM; ++d) {
        float acc = inb[d] + sdot[d] + (cond ? tbs[d] : 0.0f);
        #pragma unroll
        for (int k = 0; k < 17; ++k)
            acc = fmaf(feats[tx][k], Ws[k][d], acc);
        Ub[baseb + (size_t)d * LTR] = __float2bfloat16(acc);
    }
}

// ---------------------------------------------------------------------------
// 3a) per-layer per-channel matrix prep with BN folding + stats finalize
// ---------------------------------------------------------------------------
__global__ __launch_bounds__(256) void prep_kernel(
    const float* __restrict__ log_dt,
    const float* __restrict__ A_re, const float* __restrict__ A_im,
    const float* __restrict__ C_re, const float* __restrict__ C_im,
    const float* __restrict__ Dp,
    const float* __restrict__ gamma, const float* __restrict__ beta,
    float* __restrict__ stats, float* __restrict__ scsh,
    __hip_bfloat16* __restrict__ Abig, __hip_bfloat16* __restrict__ SA,
    float* __restrict__ Rsh, float* __restrict__ T1sh, int layer) {
    int d = blockIdx.x;
    int t = threadIdx.x;
    __shared__ float sAr[64], sAi[64], sCkr[64], sCki[64];
    __shared__ float kap[TCH];
    __shared__ float csum[TCH];
    __shared__ float s_sc, s_sh;

    if (t == 0) {
        float sc, sh;
        if (layer == 0) { sc = 1.0f; sh = 0.0f; }
        else {
            float s = stats[d], q = stats[DM + d];
            float mean = s * (1.0f / NTOT);
            float var  = q * (1.0f / NTOT) - mean * mean;
            sc = rsqrtf(var + 1e-5f) * gamma[(layer - 1) * DM + d];
            sh = beta[(layer - 1) * DM + d] - mean * sc;
        }
        s_sc = sc; s_sh = sh;
        scsh[d] = sc; scsh[DM + d] = sh;
        stats[d] = 0.0f; stats[DM + d] = 0.0f;
    }
    __syncthreads();
    float sc = s_sc, sh = s_sh;

    float dt = expf(log_dt[layer * DM + d]);
    float Dd = Dp[layer * DM + d];
    if (t < 64) {
        size_t ab = ((size_t)layer * DM + d) * DS + t;
        float Ar = A_re[ab], Ai = A_im[ab], Cr = C_re[ab], Ci = C_im[ab];
        float ar = dt * Ar, ai = dt * Ai;
        float e = expf(ar);
        float wre = e * cosf(ai), wim = e * sinf(ai);
        float mr = wre - 1.0f, mi = wim;
        float den = 1.0f / (Ar * Ar + Ai * Ai);
        float qr = (mr * Ar + mi * Ai) * den, qi = (mi * Ar - mr * Ai) * den;
        sCkr[t] = Cr * qr - Ci * qi;
        sCki[t] = Cr * qi + Ci * qr;
        sAr[t] = ar;
        sAi[t] = ai;
        float s2 = sinf(0.5f * ai);
        float dr = fmaf(expm1f(ar), cosf(ai), -2.0f * s2 * s2);
        float di = e * sinf(ai);
        float a128 = 128.0f * ar, b128 = 128.0f * ai;
        float s2b = sinf(0.5f * b128);
        float nr = fmaf(expm1f(a128), cosf(b128), -2.0f * s2b * s2b);
        float ni = expf(a128) * sinf(b128);
        float dd2 = 1.0f / (dr * dr + di * di);
        float gr = (nr * dr + ni * di) * dd2;
        float gi = (ni * dr - nr * di) * dd2;
        Rsh[(size_t)d * 128 + t]      = sh * gr;
        Rsh[(size_t)d * 128 + 64 + t] = sh * gi;
    }
    __syncthreads();

    {
        int delta = t >> 1, half = t & 1;
        float fd = (float)delta;
        float p = 0.0f;
        #pragma unroll 8
        for (int n = half * 32; n < half * 32 + 32; ++n) {
            float er = fexp_(fd * sAr[n]);
            float ph = fd * sAi[n];
            p += er * (sCkr[n] * fcos_(ph) - sCki[n] * fsin_(ph));
        }
        p += __shfl_xor(p, 1);
        if (half == 0) kap[delta] = 2.0f * p + (delta == 0 ? Dd : 0.0f);
    }
    __syncthreads();

    if (t < 128) csum[t] = kap[t];
    __syncthreads();
    for (int off = 1; off < 128; off <<= 1) {
        float v = 0.0f;
        if (t >= off && t < 128) v = csum[t - off];
        __syncthreads();
        if (t < 128) csum[t] += v;
        __syncthreads();
    }
    if (t < 128) T1sh[(size_t)d * 128 + t] = sh * csum[t];

    __hip_bfloat16* Ad = Abig + (size_t)d * TCH * 256;
    for (int idx = t; idx < TCH * TCH; idx += 256) {
        int i = idx >> 7, m = idx & 127;
        Ad[(size_t)i * 256 + m] = __float2bfloat16(m <= i ? sc * kap[i - m] : 0.0f);
    }
    for (int idx = t; idx < TCH * 64; idx += 256) {
        int i = idx >> 6, n = idx & 63;
        float fp = (float)(i + 1);
        float er = fexp_(fp * sAr[n]);
        float ph = fp * sAi[n];
        float c = fcos_(ph), s = fsin_(ph);
        float vr = er * (sCkr[n] * c - sCki[n] * s);
        float vi = er * (sCkr[n] * s + sCki[n] * c);
        Ad[(size_t)i * 256 + 128 + n] = __float2bfloat16(2.0f * vr);
        Ad[(size_t)i * 256 + 192 + n] = __float2bfloat16(-2.0f * vi);
    }
    __hip_bfloat16* Sd = SA + (size_t)d * TCH * TCH;
    for (int idx = t; idx < 64 * TCH; idx += 256) {
        int n = idx >> 7, m = idx & 127;
        float fp = (float)(127 - m);
        float er = sc * fexp_(fp * sAr[n]);
        float ph = fp * sAi[n];
        Sd[(size_t)n * 128 + m]        = __float2bfloat16(er * fcos_(ph));
        Sd[(size_t)(64 + n) * 128 + m] = __float2bfloat16(er * fsin_(ph));
    }
}

// ---------------------------------------------------------------------------
// 3b) S-GEMM, 3 tiles per block, rotating 3-region LDS pipeline. (R5)
// ---------------------------------------------------------------------------
__global__ __launch_bounds__(256) void sgemm_kernel(
    const __hip_bfloat16* __restrict__ Ub, const __hip_bfloat16* __restrict__ SA,
    const float* __restrict__ Rsh, __hip_bfloat16* __restrict__ S) {
    int id = blockIdx.x;               // 768 blocks
    int xcd = id & 7, j = id >> 3;     // j in [0,96)
    int dj = (j * 21846) >> 16;        // j/3
    int d = xcd * 32 + dj;
    int g = j - dj * 3;                // cb group: cb = 3g + t
    int tid = threadIdx.x, wave = tid >> 6, lane = tid & 63;
    int lm = lane & 15, quad = lane >> 4;
    const __hip_bfloat16* SAd = SA + (size_t)d * TCH * TCH;

    __shared__ short Bs[12288];        // 24 KB: 3 regions x 8 KB

    short8 a0r[4], a1r[4];
    #pragma unroll
    for (int kk = 0; kk < 4; ++kk) {
        a0r[kk] = *(const short8*)(SAd + (size_t)(wave * 32 + lm) * TCH + kk * 32 + quad * 8);
        a1r[kk] = *(const short8*)(SAd + (size_t)(wave * 32 + 16 + lm) * TCH + kk * 32 + quad * 8);
    }

    int ntS = (tid >> 6) & 3, qS = (tid >> 4) & 3, ccS = tid & 15;
    const __hip_bfloat16* srcB[3];
    #pragma unroll
    for (int t = 0; t < 3; ++t) {
        int col = (3 * g + t) * 64 + ntS * 16 + ccS;
        int colc = col < COLS ? col : COLS - 1;
        int bh = (colc * 241) >> 12;
        int c = colc - bh * 17;
        srcB[t] = Ub + ((size_t)bh * DM + d) * LTR + (size_t)c * TCH + qS * 8;
    }

    float4 rs0 = *(const float4*)(Rsh + (size_t)d * 128 + wave * 32 + quad * 4);
    float4 rs1 = *(const float4*)(Rsh + (size_t)d * 128 + wave * 32 + 16 + quad * 4);

    floatx4 acc[2][4];
    floatx4 zf = {0.f, 0.f, 0.f, 0.f};
    #pragma unroll
    for (int mi = 0; mi < 2; ++mi)
        #pragma unroll
        for (int nt = 0; nt < 4; ++nt) acc[mi][nt] = zf;

#define SG_STAGE(t_, kk0_, off_)                                              \
    {                                                                         \
        glds16(srcB[t_] + (kk0_) * 32,     (char*)Bs + (off_) + tid * 16);    \
        glds16(srcB[t_] + (kk0_ + 1) * 32, (char*)Bs + (off_) + 4096 + tid * 16); \
    }
#define SG_COMP(off_, kkA_)                                                   \
    {                                                                         \
        const short* bb_ = (const short*)((const char*)Bs + (off_));          \
        _Pragma("unroll")                                                     \
        for (int kk_ = 0; kk_ < 2; ++kk_) {                                   \
            _Pragma("unroll")                                                 \
            for (int nt_ = 0; nt_ < 4; ++nt_) {                               \
                short8 bv = *(const short8*)(bb_ + kk_ * 2048 + nt_ * 512 + lane * 8); \
                acc[0][nt_] = __builtin_amdgcn_mfma_f32_16x16x32_bf16(        \
                    a0r[(kkA_) + kk_], bv, acc[0][nt_], 0, 0, 0);             \
                acc[1][nt_] = __builtin_amdgcn_mfma_f32_16x16x32_bf16(        \
                    a1r[(kkA_) + kk_], bv, acc[1][nt_], 0, 0, 0);             \
            }                                                                 \
        }                                                                     \
    }
#define SG_EPI(cb_)                                                           \
    _Pragma("unroll")                                                         \
    for (int mi = 0; mi < 2; ++mi) {                                          \
        int row = wave * 32 + mi * 16 + quad * 4;                             \
        float4 rs = mi ? rs1 : rs0;                                           \
        _Pragma("unroll")                                                     \
        for (int nt_ = 0; nt_ < 4; ++nt_) {                                   \
            int col = (cb_) * 64 + nt_ * 16 + lm;                             \
            if (col < COLS) {                                                 \
                short4v o;                                                    \
                o[0] = bfs(acc[mi][nt_][0] + rs.x);                           \
                o[1] = bfs(acc[mi][nt_][1] + rs.y);                           \
                o[2] = bfs(acc[mi][nt_][2] + rs.z);                           \
                o[3] = bfs(acc[mi][nt_][3] + rs.w);                           \
                *(short4v*)(S + ((size_t)d * COLS + col) * TCH + row) = o;    \
            }                                                                 \
            acc[mi][nt_] = zf;                                                \
        }                                                                     \
    }

    SG_STAGE(0, 0, 0);
    SG_STAGE(0, 2, 8192);
    SG_STAGE(1, 0, 16384);
    BARV(4);
    SG_COMP(0, 0);
    BARV(2);
    SG_STAGE(1, 2, 0);
    SG_COMP(8192, 2);
    BARV(2);
    SG_STAGE(2, 0, 8192);
    SG_EPI(3 * g + 0);
    BARV(4);
    SG_COMP(16384, 0);
    BARV(2);
    SG_STAGE(2, 2, 16384);
    SG_COMP(0, 2);
    SG_EPI(3 * g + 1);
    BARV(2);
    SG_COMP(8192, 0);
    BARV(0);
    SG_COMP(16384, 2);
    SG_EPI(3 * g + 2);

#undef SG_STAGE
#undef SG_COMP
#undef SG_EPI
}

// ---------------------------------------------------------------------------
// 3c) carry scan over chunks (in place), loads prefetched up front
// ---------------------------------------------------------------------------
__global__ __launch_bounds__(64) void carry_kernel(
    __hip_bfloat16* __restrict__ SX,
    const float* __restrict__ log_dt,
    const float* __restrict__ A_re, const float* __restrict__ A_im,
    int layer) {
    int d = blockIdx.x, b = blockIdx.y;
    int n = threadIdx.x;
    float dt = expf(log_dt[layer * DM + d]);
    size_t ab = ((size_t)layer * DM + d) * DS + n;
    float Ar = A_re[ab], Ai = A_im[ab];
    float e = expf(dt * Ar);
    float wre = e * cosf(dt * Ai), wim = e * sinf(dt * Ai);
    #pragma unroll
    for (int t = 0; t < 7; ++t) {
        float r = wre * wre - wim * wim;
        wim = 2.0f * wre * wim; wre = r;
    }
    size_t base = ((size_t)d * COLS + (size_t)b * NC) * TCH + n;
    float sre[NC], sim[NC];
    #pragma unroll
    for (int c = 0; c < NC; ++c) {
        sre[c] = __bfloat162float(SX[base + (size_t)c * TCH]);
        sim[c] = __bfloat162float(SX[base + (size_t)c * TCH + 64]);
    }
    float xr = 0.0f, xi = 0.0f;
    #pragma unroll
    for (int c = 0; c < NC; ++c) {
        SX[base + (size_t)c * TCH]      = __float2bfloat16(xr);
        SX[base + (size_t)c * TCH + 64] = __float2bfloat16(xi);
        float nr = wre * xr - wim * xi + sre[c];
        xi = wre * xi + wim * xr + sim[c];
        xr = nr;
    }
}

// ---------------------------------------------------------------------------
// 3d) main chunk GEMM, 3 tiles per block, rotating 3x16KB LDS pipeline. (R5)
// ---------------------------------------------------------------------------
__global__ __launch_bounds__(256) void mainscan_kernel(
    const __hip_bfloat16* __restrict__ Ub, const __hip_bfloat16* __restrict__ X,
    const __hip_bfloat16* __restrict__ Abig, const float* __restrict__ T1sh,
    __hip_bfloat16* __restrict__ Ybt) {
    int id = blockIdx.x;               // 768 blocks
    int xcd = id & 7, j = id >> 3;     // j in [0,96)
    int dj = (j * 21846) >> 16;        // j/3
    int d = xcd * 32 + dj;
    int g = j - dj * 3;                // cb = 3g + t
    int tid = threadIdx.x, wave = tid >> 6, lane = tid & 63;
    int lm = lane & 15, quad = lane >> 4;
    const __hip_bfloat16* Ad = Abig + (size_t)d * TCH * 256;

    __shared__ short Bs[24576];        // 48 KB: 3 regions x 16 KB

    short8 a0r[8], a1r[8];
    #pragma unroll
    for (int kk = 0; kk < 8; ++kk) {
        a0r[kk] = *(const short8*)(Ad + (size_t)(wave * 32 + lm) * 256 + kk * 32 + quad * 8);
        a1r[kk] = *(const short8*)(Ad + (size_t)(wave * 32 + 16 + lm) * 256 + kk * 32 + quad * 8);
    }

    int ntS = (tid >> 6) & 3, qS = (tid >> 4) & 3, ccS = tid & 15;
    const __hip_bfloat16* srcU[3];
    const __hip_bfloat16* srcX[3];
    #pragma unroll
    for (int t = 0; t < 3; ++t) {
        int col = (3 * g + t) * 64 + ntS * 16 + ccS;
        int colc = col < COLS ? col : COLS - 1;
        int bh = (colc * 241) >> 12;
        int c = colc - bh * 17;
        srcU[t] = Ub + ((size_t)bh * DM + d) * LTR + (size_t)c * TCH + qS * 8;
        srcX[t] = X + ((size_t)d * COLS + colc) * TCH + qS * 8;
    }

    float4 t1a = *(const float4*)(T1sh + (size_t)d * 128 + wave * 32 + quad * 4);
    float4 t1b = *(const float4*)(T1sh + (size_t)d * 128 + wave * 32 + 16 + quad * 4);

    floatx4 acc[2][4];
    floatx4 zf = {0.f, 0.f, 0.f, 0.f};
    #pragma unroll
    for (int mi = 0; mi < 2; ++mi)
        #pragma unroll
        for (int nt = 0; nt < 4; ++nt) acc[mi][nt] = zf;

#define MS_STAGE_LO(t_, off_)                                                 \
    {                                                                         \
        _Pragma("unroll")                                                     \
        for (int k_ = 0; k_ < 4; ++k_)                                        \
            glds16(srcU[t_] + k_ * 32,                                        \
                   (char*)Bs + (off_) + k_ * 4096 + tid * 16);                \
    }
#define MS_STAGE_HI(t_, off_)                                                 \
    {                                                                         \
        _Pragma("unroll")                                                     \
        for (int k_ = 0; k_ < 4; ++k_)                                        \
            glds16(srcX[t_] + k_ * 32,                                        \
                   (char*)Bs + (off_) + k_ * 4096 + tid * 16);                \
    }
#define MS_COMP(off_, kkA_)                                                   \
    {                                                                         \
        const short* bb_ = (const short*)((const char*)Bs + (off_));          \
        _Pragma("unroll")                                                     \
        for (int kk_ = 0; kk_ < 4; ++kk_) {                                   \
            _Pragma("unroll")                                                 \
            for (int nt_ = 0; nt_ < 4; ++nt_) {                               \
                short8 bv = *(const short8*)(bb_ + kk_ * 2048 + nt_ * 512 + lane * 8); \
                acc[0][nt_] = __builtin_amdgcn_mfma_f32_16x16x32_bf16(        \
                    a0r[(kkA_) + kk_], bv, acc[0][nt_], 0, 0, 0);             \
                acc[1][nt_] = __builtin_amdgcn_mfma_f32_16x16x32_bf16(        \
                    a1r[(kkA_) + kk_], bv, acc[1][nt_], 0, 0, 0);             \
            }                                                                 \
        }                                                                     \
    }
#define MS_EPI(cb_)                                                           \
    _Pragma("unroll")                                                         \
    for (int mi = 0; mi < 2; ++mi) {                                          \
        int row0 = wave * 32 + mi * 16 + quad * 4;                            \
        float4 t1 = mi ? t1b : t1a;                                           \
        _Pragma("unroll")                                                     \
        for (int nt_ = 0; nt_ < 4; ++nt_) {                                   \
            int col = (cb_) * 64 + nt_ * 16 + lm;                             \
            if (col < COLS) {                                                 \
                int bh = (col * 241) >> 12;                                   \
                int c = col - bh * 17;                                        \
                int l0 = c * TCH + row0;                                      \
                float g0 = gelu_tanh(acc[mi][nt_][0] + t1.x);                 \
                float g1 = gelu_tanh(acc[mi][nt_][1] + t1.y);                 \
                float g2 = gelu_tanh(acc[mi][nt_][2] + t1.z);                 \
                float g3 = gelu_tanh(acc[mi][nt_][3] + t1.w);                 \
                __hip_bfloat16* dst = Ybt + ((size_t)bh * DM + d) * LTR + l0; \
                if (l0 + 3 < LT) {                                            \
                    short4v o;                                                \
                    o[0] = bfs(g0); o[1] = bfs(g1);                           \
                    o[2] = bfs(g2); o[3] = bfs(g3);                           \
                    *(short4v*)dst = o;                                       \
                } else {                                                      \
                    if (l0 + 0 < LT) dst[0] = __float2bfloat16(g0);           \
                    if (l0 + 1 < LT) dst[1] = __float2bfloat16(g1);           \
                    if (l0 + 2 < LT) dst[2] = __float2bfloat16(g2);           \
                    if (l0 + 3 < LT) dst[3] = __float2bfloat16(g3);           \
                }                                                             \
            }                                                                 \
            acc[mi][nt_] = zf;                                                \
        }                                                                     \
    }

    MS_STAGE_LO(0, 0);
    MS_STAGE_HI(0, 16384);
    MS_STAGE_LO(1, 32768);
    BARV(8);
    MS_COMP(0, 0);
    BARV(4);
    MS_STAGE_HI(1, 0);
    MS_COMP(16384, 4);
    BARV(4);
    MS_STAGE_LO(2, 16384);
    MS_EPI(3 * g + 0);
    BARV(8);
    MS_COMP(32768, 0);
    BARV(4);
    MS_STAGE_HI(2, 32768);
    MS_COMP(0, 4);
    MS_EPI(3 * g + 1);
    BARV(4);
    MS_COMP(16384, 0);
    BARV(0);
    MS_COMP(32768, 4);
    MS_EPI(3 * g + 2);

#undef MS_STAGE_LO
#undef MS_STAGE_HI
#undef MS_COMP
#undef MS_EPI
}

// ---------------------------------------------------------------------------
// 4) GEMM + GLU + residual + BN stats.  R5 skeleton (2176 blocks, one by per
//    block, BK=32 A double-buffer) + R7's verified direct global->reg B path.
//    LDS = 16 KB (2 x 8 KB A buffers); barriers are lgkm-only so B loads stay
//    in flight across them; B regs double-buffered one substep ahead.
// ---------------------------------------------------------------------------
__global__ __launch_bounds__(256) void gemm_glu_mfma_kernel(
    const __hip_bfloat16* __restrict__ Ybt, __hip_bfloat16* __restrict__ Ub,
    const __hip_bfloat16* __restrict__ Wtp, const float* __restrict__ out_b,
    const float* __restrict__ scsh, float* __restrict__ stats, int layer) {
    int id = blockIdx.x;               // 2176 blocks
    int r8 = id & 7, j = id >> 3;      // j in [0,272)
    int by = r8 >> 1;
    int sub = (r8 & 1) * 272 + j;      // [0,544)
    int bq = (sub * 3856) >> 16;       // sub/17
    int bx = sub - bq * 17;
    int b = bq;
    int tid = threadIdx.x;
    int wave = tid >> 6, lane = tid & 63;
    int lm = lane & 15, quad = lane >> 4;
    int l0 = bx * 128;

    __shared__ short lds[8192];        // 16 KB: 2 x (128l x 32k) A buffers

    // ---- A-staging mapping (R5-verified): thread = (kp, l8) ----
    int kp = tid >> 4;
    int l8 = tid & 15;
    const __hip_bfloat16* srcA = Ybt + ((size_t)b * DM + 2 * kp) * LTR + l0 + l8 * 8;
    int woff[8];
    {
        int qA = kp >> 2;
        #pragma unroll
        for (int jj = 0; jj < 8; ++jj) {
            int lloc = l8 * 8 + jj;
            int s4 = (qA + lloc + l8) & 3;      // (lloc>>3) == l8
            woff[jj] = lloc * 32 + s4 * 8 + (kp & 3) * 2;
        }
    }
    // ---- A fragment read offsets (region-local, R5-verified) ----
    int aoff[4];
    #pragma unroll
    for (int mi = 0; mi < 4; ++mi) {
        int r = (wave >> 1) * 64 + mi * 16 + lm;
        aoff[mi] = r * 32 + ((quad + r + (r >> 3)) & 3) * 8;
    }
    // ---- B direct-load base (R7-verified): frag(ni,S) = srcBF + ni*4096 + S*32
    const __hip_bfloat16* srcBF = Wtp + (size_t)layer * 512 * 256
                                + (size_t)by * 128 * 256
                                + (size_t)((wave & 1) * 64 + lm) * 256 + quad * 8;

    floatx4 acc[4][4];
    floatx4 zf = {0.f, 0.f, 0.f, 0.f};
    #pragma unroll
    for (int mi = 0; mi < 4; ++mi)
        #pragma unroll
        for (int ni = 0; ni < 4; ++ni) acc[mi][ni] = zf;

    const float* bl = out_b + layer * 512;
    int lwq = l0 + (wave >> 1) * 64;

#define LOAD_A(S, G0, G1)                                                     \
    {                                                                         \
        const __hip_bfloat16* pa_ = srcA + (size_t)(S) * 32 * LTR;            \
        G0 = *(const short8*)pa_;                                             \
        G1 = *(const short8*)(pa_ + LTR);                                     \
    }
#define WRITE_A(P, G0, G1)                                                    \
    {                                                                         \
        short* ab_ = lds + (P) * 4096;                                        \
        _Pragma("unroll")                                                     \
        for (int j_ = 0; j_ < 8; ++j_) {                                      \
            unsigned pk_ = (unsigned)(unsigned short)G0[j_] |                 \
                           ((unsigned)(unsigned short)G1[j_] << 16);          \
            *(unsigned*)(ab_ + woff[j_]) = pk_;                               \
        }                                                                     \
    }
#define LOADB(S, F)                                                           \
    {                                                                         \
        const __hip_bfloat16* pb_ = srcBF + (S) * 32;                         \
        _Pragma("unroll")                                                     \
        for (int ni_ = 0; ni_ < 4; ++ni_)                                     \
            F[ni_] = *(const short8*)(pb_ + ni_ * 4096);                      \
    }
#define COMPUTE(P, F)                                                         \
    {                                                                         \
        const short* ab_ = lds + (P) * 4096;                                  \
        short8 af_[4];                                                        \
        _Pragma("unroll")                                                     \
        for (int mi_ = 0; mi_ < 4; ++mi_)                                     \
            af_[mi_] = *(const short8*)(ab_ + aoff[mi_]);                     \
        _Pragma("unroll")                                                     \
        for (int mi_ = 0; mi_ < 4; ++mi_)                                     \
            _Pragma("unroll")                                                 \
            for (int ni_ = 0; ni_ < 4; ++ni_)                                 \
                acc[mi_][ni_] = __builtin_amdgcn_mfma_f32_16x16x32_bf16(      \
                    af_[mi_], F[ni_], acc[mi_][ni_], 0, 0, 0);                \
    }

    short8 gE0, gE1, gO0, gO1;
    short8 bf0[4], bf1[4];

    // prologue: A(0) staged to buf0; A(1)+B(0,1) in flight
    LOAD_A(0, gE0, gE1);
    LOADB(0, bf0);
    WRITE_A(0, gE0, gE1);
    LOAD_A(1, gO0, gO1);
    LOADB(1, bf1);
    BARL;                               // buf0 visible to all waves

    // s=0..6: compute buf(s&1) with bf(s&1); stage A(s+1); prefetch A(s+2), B(s+2)
    COMPUTE(0, bf0); WRITE_A(1, gO0, gO1); LOAD_A(2, gE0, gE1); LOADB(2, bf0); BARL;
    COMPUTE(1, bf1); WRITE_A(0, gE0, gE1); LOAD_A(3, gO0, gO1); LOADB(3, bf1); BARL;
    COMPUTE(0, bf0); WRITE_A(1, gO0, gO1); LOAD_A(4, gE0, gE1); LOADB(4, bf0); BARL;
    COMPUTE(1, bf1); WRITE_A(0, gE0, gE1); LOAD_A(5, gO0, gO1); LOADB(5, bf1); BARL;
    COMPUTE(0, bf0); WRITE_A(1, gO0, gO1); LOAD_A(6, gE0, gE1); LOADB(6, bf0); BARL;
    COMPUTE(1, bf1); WRITE_A(0, gE0, gE1); LOAD_A(7, gO0, gO1); LOADB(7, bf1); BARL;
    COMPUTE(0, bf0); WRITE_A(1, gO0, gO1); BARL;
    COMPUTE(1, bf1);

#undef LOAD_A
#undef WRITE_A
#undef LOADB
#undef COMPUTE

    int Pbase = by * 64 + (wave & 1) * 32;
    #pragma unroll
    for (int ni = 0; ni < 2; ++ni) {
        int P = Pbase + ni * 16 + lm;
        float bz1 = bl[P], bz2 = bl[256 + P];
        float scP = scsh[P], shP = scsh[DM + P];
        __hip_bfloat16* ubrow = Ub + ((size_t)b * DM + P) * LTR;
        float sp = 0.f, sq = 0.f;
        #pragma unroll
        for (int mi = 0; mi < 4; ++mi) {
            int l0q = lwq + mi * 16 + quad * 4;
            if (l0q >= LT) continue;
            floatx4 z1 = acc[mi][ni];
            floatx4 z2 = acc[mi][ni + 2];
            if (l0q + 4 <= LT) {
                short4v uv = *(const short4v*)(ubrow + l0q);
                float h0 = fmaf(scP, sbf(uv[0]), shP) + (z1[0] + bz1) * sigmoidf_(z2[0] + bz2);
                float h1 = fmaf(scP, sbf(uv[1]), shP) + (z1[1] + bz1) * sigmoidf_(z2[1] + bz2);
                float h2 = fmaf(scP, sbf(uv[2]), shP) + (z1[2] + bz1) * sigmoidf_(z2[2] + bz2);
                float h3 = fmaf(scP, sbf(uv[3]), shP) + (z1[3] + bz1) * sigmoidf_(z2[3] + bz2);
                short4v ov;
                ov[0] = bfs(h0); ov[1] = bfs(h1); ov[2] = bfs(h2); ov[3] = bfs(h3);
                *(short4v*)(ubrow + l0q) = ov;
                sp += (h0 + h1) + (h2 + h3);
                sq += (h0 * h0 + h1 * h1) + (h2 * h2 + h3 * h3);
            } else {
                #pragma unroll
                for (int r = 0; r < 4; ++r) {
                    int l = l0q + r;
                    if (l < LT) {
                        float uvv = __bfloat162float(ubrow[l]);
                        float hh = fmaf(scP, uvv, shP) + (z1[r] + bz1) * sigmoidf_(z2[r] + bz2);
                        ubrow[l] = __float2bfloat16(hh);
                        sp += hh; sq += hh * hh;
                    }
                }
            }
        }
        sp += __shfl_xor(sp, 16); sp += __shfl_xor(sp, 32);
        sq += __shfl_xor(sq, 16); sq += __shfl_xor(sq, 32);
        if (quad == 0) {
            atomicAdd(&stats[P], sp);
            atomicAdd(&stats[DM + P], sq);
        }
    }
}

// ---------------------------------------------------------------------------
// 5) final stats -> (sc, sh) for head
// ---------------------------------------------------------------------------
__global__ __launch_bounds__(256) void statsfin_kernel(
    const float* __restrict__ stats,
    const float* __restrict__ gamma, const float* __restrict__ beta,
    float* __restrict__ scsh, int layer) {
    int d = threadIdx.x;
    float s = stats[d], q = stats[DM + d];
    float mean = s * (1.0f / NTOT);
    float var  = q * (1.0f / NTOT) - mean * mean;
    float sc = rsqrtf(var + 1e-5f) * gamma[layer * DM + d];
    scsh[d] = sc;
    scsh[DM + d] = beta[layer * DM + d] - mean * sc;
}

// ---------------------------------------------------------------------------
// 6) head
// ---------------------------------------------------------------------------
__global__ __launch_bounds__(128) void head_kernel(
    const __hip_bfloat16* __restrict__ Ub, const float* __restrict__ scsh,
    const float* __restrict__ W1, const float* __restrict__ b1,
    const float* __restrict__ W2, const float* __restrict__ b2,
    float* __restrict__ out) {
    int hh = blockIdx.x;
    int b  = blockIdx.y;
    int j  = threadIdx.x;
    int l  = (L_ - 1) + hh;
    const __hip_bfloat16* urow = Ub + ((size_t)b * DM) * LTR + l;
    float a = b1[j];
    for (int k = 0; k < DM; ++k) {
        float hn = fmaf(scsh[k], __bfloat162float(urow[(size_t)k * LTR]), scsh[DM + k]);
        a = fmaf(hn, W1[k * 128 + j], a);
    }
    float hs = a * sigmoidf_(a);
    float v = hs * W2[j];
    v += __shfl_xor(v, 1);
    v += __shfl_xor(v, 2);
    v += __shfl_xor(v, 4);
    v += __shfl_xor(v, 8);
    v += __shfl_xor(v, 16);
    v += __shfl_xor(v, 32);
    __shared__ float partial[2];
    if ((j & 63) == 0) partial[j >> 6] = v;
    __syncthreads();
    if (j == 0) out[b * H_ + hh] = partial[0] + partial[1] + b2[0];
}

// ---------------------------------------------------------------------------
extern "C" void kernel_launch(void* const* d_in, const int* in_sizes, int n_in,
                              void* d_out, int out_size, void* d_ws, size_t ws_size,
                              hipStream_t stream) {
    (void)in_sizes; (void)n_in; (void)out_size; (void)ws_size;
    const float* x_past      = (const float*)d_in[0];
    const float* noisy       = (const float*)d_in[1];
    const float* t_in        = (const float*)d_in[2];
    const float* x_future    = (const float*)d_in[3];
    const float* static_attr = (const float*)d_in[4];
    const float* freqs       = (const float*)d_in[5];
    const float* phases      = (const float*)d_in[6];
    const float* in_W        = (const float*)d_in[7];
    const float* in_b        = (const float*)d_in[8];
    const float* tm_W1       = (const float*)d_in[9];
    const float* tm_b1       = (const float*)d_in[10];
    const float* tm_W2       = (const float*)d_in[11];
    const float* tm_b2       = (const float*)d_in[12];
    const float* log_dt      = (const float*)d_in[13];
    const float* A_re        = (const float*)d_in[14];
    const float* A_im        = (const float*)d_in[15];
    const float* C_re        = (const float*)d_in[16];
    const float* C_im        = (const float*)d_in[17];
    const float* Dp          = (const float*)d_in[18];
    const float* out_W       = (const float*)d_in[19];
    const float* out_b       = (const float*)d_in[20];
    const float* bn_gamma    = (const float*)d_in[21];
    const float* bn_beta     = (const float*)d_in[22];
    const float* head_W1     = (const float*)d_in[23];
    const float* head_b1     = (const float*)d_in[24];
    const float* head_W2     = (const float*)d_in[25];
    const float* head_b2     = (const float*)d_in[26];

    char* ws = (char*)d_ws;
    const size_t UB_OFF = 1u << 20;
    const size_t UB_BYT = (size_t)B_ * DM * LTR * 2;
    const size_t R1_OFF = UB_OFF + UB_BYT;
    const size_t RB     = (size_t)256 * COLS * TCH * 2;
    const size_t R2_OFF = R1_OFF + RB;
    const size_t AB_OFF = R2_OFF + RB;
    const size_t AB_BYT = (size_t)256 * TCH * 256 * 2;
    const size_t SA_OFF = AB_OFF + AB_BYT;
    const size_t SA_BYT = (size_t)256 * TCH * TCH * 2;
    const size_t WT_OFF = SA_OFF + SA_BYT;

    float*          tb    = (float*)(ws);
    float*          stats = (float*)(ws + (64 << 10));
    float*          scsh  = (float*)(ws + (96 << 10));
    float*          Rsh   = (float*)(ws + (128 << 10));
    float*          T1sh  = (float*)(ws + (256 << 10));
    __hip_bfloat16* Ub    = (__hip_bfloat16*)(ws + UB_OFF);
    __hip_bfloat16* R1    = (__hip_bfloat16*)(ws + R1_OFF);
    __hip_bfloat16* Ybt   = (__hip_bfloat16*)(ws + R2_OFF);
    __hip_bfloat16* Abig  = (__hip_bfloat16*)(ws + AB_OFF);
    __hip_bfloat16* SA    = (__hip_bfloat16*)(ws + SA_OFF);
    __hip_bfloat16* Wtp   = (__hip_bfloat16*)(ws + WT_OFF);

    time_mlp_kernel<<<dim3(B_), 256, 0, stream>>>(
        t_in, freqs, phases, tm_W1, tm_b1, tm_W2, tm_b2, tb);

    wt_prep_kernel<<<dim3(NL * 256), 256, 0, stream>>>(out_W, Wtp);

    input_proj_kernel<<<dim3(9, B_), 256, 0, stream>>>(
        x_past, noisy, x_future, static_attr, in_W, in_b, tb, Ub);

    for (int layer = 0; layer < NL; ++layer) {
        prep_kernel<<<dim3(256), 256, 0, stream>>>(
            log_dt, A_re, A_im, C_re, C_im, Dp, bn_gamma, bn_beta,
            stats, scsh, Abig, SA, Rsh, T1sh, layer);
        sgemm_kernel<<<dim3(768), 256, 0, stream>>>(Ub, SA, Rsh, R1);
        carry_kernel<<<dim3(256, B_), 64, 0, stream>>>(
            R1, log_dt, A_re, A_im, layer);
        mainscan_kernel<<<dim3(768), 256, 0, stream>>>(Ub, R1, Abig, T1sh, Ybt);
        gemm_glu_mfma_kernel<<<dim3(2176), 256, 0, stream>>>(
            Ybt, Ub, Wtp, out_b, scsh, stats, layer);
    }

    statsfin_kernel<<<dim3(1), 256, 0, stream>>>(
        stats, bn_gamma, bn_beta, scsh, NL - 1);

    head_kernel<<<dim3(H_, B_), 128, 0, stream>>>(
        Ub, scsh, head_W1, head_b1, head_W2, head_b2, (float*)d_out);
}

// Round 9
// 695.530 us; speedup vs baseline: 1.3095x; 1.1178x over previous
//
#include <hip/hip_runtime.h>
#include <hip/hip_bf16.h>
#include <math.h>

#define B_   32
#define L_   2048
#define H_   8
#define DMET 16
#define SDIM 27
#define DM   256
#define NL   4
#define DS   64
#define TE   256
#define LT   2055          // L + H - 1
#define LTR  2176          // 17*128: padded l for Ub/Ybt
#define TCH  128           // chunk length
#define NC   17            // chunks per sequence
#define COLS 544           // B_ * NC
#define NTOT (B_ * LT)

typedef __attribute__((ext_vector_type(8))) short short8;
typedef __attribute__((ext_vector_type(4))) short short4v;
typedef __attribute__((ext_vector_type(4))) float floatx4;

// fast sigmoid: 1/(1+2^(-x*log2 e)) via v_exp_f32 + v_rcp_f32.
__device__ __forceinline__ float sigmoidf_(float x) {
    float e = __builtin_amdgcn_exp2f(-1.4426950408889634f * x);
    return __builtin_amdgcn_rcpf(1.0f + e);
}

// tanh-gelu in sigmoid form: 0.5*(1+tanh(z)) == sigmoid(2z) exactly.
__device__ __forceinline__ float gelu_tanh(float x) {
    float inner = 1.5957691216057308f * fmaf(0.044715f * x * x, x, x);
    return x * sigmoidf_(inner);
}

// hardware exp/sin/cos (revolutions, fract-reduced).
__device__ __forceinline__ float fexp_(float x) {
    return __builtin_amdgcn_exp2f(1.4426950408889634f * x);
}
__device__ __forceinline__ float fsin_(float ph) {
    float r = ph * 0.15915494309189535f;
    r = r - floorf(r);
    return __builtin_amdgcn_sinf(r);
}
__device__ __forceinline__ float fcos_(float ph) {
    float r = ph * 0.15915494309189535f;
    r = r - floorf(r);
    return __builtin_amdgcn_cosf(r);
}

__device__ __forceinline__ short bfs(float x) {
    __hip_bfloat16 h = __float2bfloat16(x);
    return *(short*)&h;
}

__device__ __forceinline__ float sbf(short s) {
    unsigned u = ((unsigned)(unsigned short)s) << 16;
    return __uint_as_float(u);
}

__device__ __forceinline__ void glds16(const void* g, void* l) {
    __builtin_amdgcn_global_load_lds(
        (const __attribute__((address_space(1))) unsigned*)g,
        (__attribute__((address_space(3))) unsigned*)l, 16, 0, 0);
}

// counted-vmcnt fence + full barrier; lgkmcnt(0) drains this wave's ds ops
// so a later overwrite of the region is safe cross-wave.
#define BARV(n) do {                                                          \
    asm volatile("s_waitcnt vmcnt(" #n ") lgkmcnt(0)" ::: "memory");          \
    __builtin_amdgcn_s_barrier();                                             \
    asm volatile("" ::: "memory");                                            \
} while (0)

// ---------------------------------------------------------------------------
// 1) time MLP
// ---------------------------------------------------------------------------
__global__ __launch_bounds__(256) void time_mlp_kernel(
    const float* __restrict__ t, const float* __restrict__ freqs,
    const float* __restrict__ phases,
    const float* __restrict__ W1, const float* __restrict__ b1,
    const float* __restrict__ W2, const float* __restrict__ b2,
    float* __restrict__ tb) {
    int b = blockIdx.x;
    int tid = threadIdx.x;
    __shared__ float f[TE];
    __shared__ float hid[2 * TE];
    float tv = t[b];
    f[tid] = cosf(fmaf(tv, freqs[tid], phases[tid])) * 1.4142135623730951f;
    __syncthreads();
    float a0 = b1[tid], a1 = b1[tid + TE];
    for (int k = 0; k < TE; ++k) {
        float fk = f[k];
        a0 = fmaf(fk, W1[k * 2 * TE + tid], a0);
        a1 = fmaf(fk, W1[k * 2 * TE + tid + TE], a1);
    }
    hid[tid]      = a0 * sigmoidf_(a0);
    hid[tid + TE] = a1 * sigmoidf_(a1);
    __syncthreads();
    float acc = b2[tid];
    for (int j = 0; j < 2 * TE; ++j)
        acc = fmaf(hid[j], W2[j * DM + tid], acc);
    tb[b * DM + tid] = acc;
}

// ---------------------------------------------------------------------------
// 1b) out_W [NL][256][512] fp32 -> Wtp bf16 [NL][512 permuted cols][256 k]
// ---------------------------------------------------------------------------
__global__ __launch_bounds__(256) void wt_prep_kernel(
    const float* __restrict__ out_W, __hip_bfloat16* __restrict__ Wtp) {
    int bid = blockIdx.x;
    int layer = bid >> 8, k = bid & 255;
    int e = threadIdx.x;
    const float* src = out_W + ((size_t)layer * 256 + k) * 512;
    #pragma unroll
    for (int q = 0; q < 2; ++q) {
        int ee = e + q * 256;
        int P = ee & 255, half = ee >> 8;
        int by = P >> 6, pp = P & 63;
        int g = pp >> 5;
        int tcol = (pp & 31) + half * 32;
        int c = by * 128 + g * 64 + tcol;
        Wtp[((size_t)layer * 512 + c) * 256 + k] = __float2bfloat16(src[ee]);
    }
}

// ---------------------------------------------------------------------------
// 2) input projection -> Ub[b][d][l] bf16, zeroes pad
// ---------------------------------------------------------------------------
__global__ __launch_bounds__(256) void input_proj_kernel(
    const float* __restrict__ xp, const float* __restrict__ nf,
    const float* __restrict__ xf, const float* __restrict__ sa,
    const float* __restrict__ inW, const float* __restrict__ inb,
    const float* __restrict__ tb, __hip_bfloat16* __restrict__ Ub) {
    int b  = blockIdx.y;
    int l0 = blockIdx.x * 256;
    int tx = threadIdx.x;
    int l  = l0 + tx;

    __shared__ float feats[256][18];
    __shared__ float Ws[17][DM];
    __shared__ float sdot[DM];
    __shared__ float tbs[DM];
    __shared__ float sstat[SDIM];

    if (tx < SDIM) sstat[tx] = sa[b * SDIM + tx];
    for (int k = 0; k < 17; ++k) Ws[k][tx] = inW[k * DM + tx];
    tbs[tx] = tb[b * DM + tx];

    bool valid = (l < LT);
    if (valid) {
        const float* src = (l < L_) ? &xp[((size_t)b * L_ + l) * DMET]
                                    : &xf[((size_t)b * (H_ - 1) + (l - L_)) * DMET];
        #pragma unroll
        for (int k = 0; k < DMET; ++k) feats[tx][k] = src[k];
        feats[tx][16] = (l >= L_ - 1) ? nf[b * H_ + (l - (L_ - 1))] : 0.0f;
    }
    __syncthreads();

    float sd = 0.0f;
    for (int k = 0; k < SDIM; ++k)
        sd = fmaf(sstat[k], inW[(17 + k) * DM + tx], sd);
    sdot[tx] = sd;
    __syncthreads();

    if (l >= LTR) return;
    size_t baseb = ((size_t)b * DM) * LTR + l;
    if (!valid) {
        __hip_bfloat16 z = __float2bfloat16(0.0f);
        for (int d = 0; d < DM; ++d) Ub[baseb + (size_t)d * LTR] = z;
        return;
    }
    bool cond = (l >= L_ - 1);
    for (int d = 0; d < DM; ++d) {
        float acc = inb[d] + sdot[d] + (cond ? tbs[d] : 0.0f);
        #pragma unroll
        for (int k = 0; k < 17; ++k)
            acc = fmaf(feats[tx][k], Ws[k][d], acc);
        Ub[baseb + (size_t)d * LTR] = __float2bfloat16(acc);
    }
}

// ---------------------------------------------------------------------------
// 3a) per-layer per-channel matrix prep with BN folding + stats finalize
// ---------------------------------------------------------------------------
__global__ __launch_bounds__(256) void prep_kernel(
    const float* __restrict__ log_dt,
    const float* __restrict__ A_re, const float* __restrict__ A_im,
    const float* __restrict__ C_re, const float* __restrict__ C_im,
    const float* __restrict__ Dp,
    const float* __restrict__ gamma, const float* __restrict__ beta,
    float* __restrict__ stats, float* __restrict__ scsh,
    __hip_bfloat16* __restrict__ Abig, __hip_bfloat16* __restrict__ SA,
    float* __restrict__ Rsh, float* __restrict__ T1sh, int layer) {
    int d = blockIdx.x;
    int t = threadIdx.x;
    __shared__ float sAr[64], sAi[64], sCkr[64], sCki[64];
    __shared__ float kap[TCH];
    __shared__ float csum[TCH];
    __shared__ float s_sc, s_sh;

    if (t == 0) {
        float sc, sh;
        if (layer == 0) { sc = 1.0f; sh = 0.0f; }
        else {
            float s = stats[d], q = stats[DM + d];
            float mean = s * (1.0f / NTOT);
            float var  = q * (1.0f / NTOT) - mean * mean;
            sc = rsqrtf(var + 1e-5f) * gamma[(layer - 1) * DM + d];
            sh = beta[(layer - 1) * DM + d] - mean * sc;
        }
        s_sc = sc; s_sh = sh;
        scsh[d] = sc; scsh[DM + d] = sh;
        stats[d] = 0.0f; stats[DM + d] = 0.0f;
    }
    __syncthreads();
    float sc = s_sc, sh = s_sh;

    float dt = expf(log_dt[layer * DM + d]);
    float Dd = Dp[layer * DM + d];
    if (t < 64) {
        size_t ab = ((size_t)layer * DM + d) * DS + t;
        float Ar = A_re[ab], Ai = A_im[ab], Cr = C_re[ab], Ci = C_im[ab];
        float ar = dt * Ar, ai = dt * Ai;
        float e = expf(ar);
        float wre = e * cosf(ai), wim = e * sinf(ai);
        float mr = wre - 1.0f, mi = wim;
        float den = 1.0f / (Ar * Ar + Ai * Ai);
        float qr = (mr * Ar + mi * Ai) * den, qi = (mi * Ar - mr * Ai) * den;
        sCkr[t] = Cr * qr - Ci * qi;
        sCki[t] = Cr * qi + Ci * qr;
        sAr[t] = ar;
        sAi[t] = ai;
        float s2 = sinf(0.5f * ai);
        float dr = fmaf(expm1f(ar), cosf(ai), -2.0f * s2 * s2);
        float di = e * sinf(ai);
        float a128 = 128.0f * ar, b128 = 128.0f * ai;
        float s2b = sinf(0.5f * b128);
        float nr = fmaf(expm1f(a128), cosf(b128), -2.0f * s2b * s2b);
        float ni = expf(a128) * sinf(b128);
        float dd2 = 1.0f / (dr * dr + di * di);
        float gr = (nr * dr + ni * di) * dd2;
        float gi = (ni * dr - nr * di) * dd2;
        Rsh[(size_t)d * 128 + t]      = sh * gr;
        Rsh[(size_t)d * 128 + 64 + t] = sh * gi;
    }
    __syncthreads();

    {
        int delta = t >> 1, half = t & 1;
        float fd = (float)delta;
        float p = 0.0f;
        #pragma unroll 8
        for (int n = half * 32; n < half * 32 + 32; ++n) {
            float er = fexp_(fd * sAr[n]);
            float ph = fd * sAi[n];
            p += er * (sCkr[n] * fcos_(ph) - sCki[n] * fsin_(ph));
        }
        p += __shfl_xor(p, 1);
        if (half == 0) kap[delta] = 2.0f * p + (delta == 0 ? Dd : 0.0f);
    }
    __syncthreads();

    if (t < 128) csum[t] = kap[t];
    __syncthreads();
    for (int off = 1; off < 128; off <<= 1) {
        float v = 0.0f;
        if (t >= off && t < 128) v = csum[t - off];
        __syncthreads();
        if (t < 128) csum[t] += v;
        __syncthreads();
    }
    if (t < 128) T1sh[(size_t)d * 128 + t] = sh * csum[t];

    __hip_bfloat16* Ad = Abig + (size_t)d * TCH * 256;
    for (int idx = t; idx < TCH * TCH; idx += 256) {
        int i = idx >> 7, m = idx & 127;
        Ad[(size_t)i * 256 + m] = __float2bfloat16(m <= i ? sc * kap[i - m] : 0.0f);
    }
    for (int idx = t; idx < TCH * 64; idx += 256) {
        int i = idx >> 6, n = idx & 63;
        float fp = (float)(i + 1);
        float er = fexp_(fp * sAr[n]);
        float ph = fp * sAi[n];
        float c = fcos_(ph), s = fsin_(ph);
        float vr = er * (sCkr[n] * c - sCki[n] * s);
        float vi = er * (sCkr[n] * s + sCki[n] * c);
        Ad[(size_t)i * 256 + 128 + n] = __float2bfloat16(2.0f * vr);
        Ad[(size_t)i * 256 + 192 + n] = __float2bfloat16(-2.0f * vi);
    }
    __hip_bfloat16* Sd = SA + (size_t)d * TCH * TCH;
    for (int idx = t; idx < 64 * TCH; idx += 256) {
        int n = idx >> 7, m = idx & 127;
        float fp = (float)(127 - m);
        float er = sc * fexp_(fp * sAr[n]);
        float ph = fp * sAi[n];
        Sd[(size_t)n * 128 + m]        = __float2bfloat16(er * fcos_(ph));
        Sd[(size_t)(64 + n) * 128 + m] = __float2bfloat16(er * fsin_(ph));
    }
}

// ---------------------------------------------------------------------------
// 3b) S-GEMM, 3 tiles per block, rotating 3-region LDS pipeline. (R5)
// ---------------------------------------------------------------------------
__global__ __launch_bounds__(256) void sgemm_kernel(
    const __hip_bfloat16* __restrict__ Ub, const __hip_bfloat16* __restrict__ SA,
    const float* __restrict__ Rsh, __hip_bfloat16* __restrict__ S) {
    int id = blockIdx.x;               // 768 blocks
    int xcd = id & 7, j = id >> 3;     // j in [0,96)
    int dj = (j * 21846) >> 16;        // j/3
    int d = xcd * 32 + dj;
    int g = j - dj * 3;                // cb group: cb = 3g + t
    int tid = threadIdx.x, wave = tid >> 6, lane = tid & 63;
    int lm = lane & 15, quad = lane >> 4;
    const __hip_bfloat16* SAd = SA + (size_t)d * TCH * TCH;

    __shared__ short Bs[12288];        // 24 KB: 3 regions x 8 KB

    short8 a0r[4], a1r[4];
    #pragma unroll
    for (int kk = 0; kk < 4; ++kk) {
        a0r[kk] = *(const short8*)(SAd + (size_t)(wave * 32 + lm) * TCH + kk * 32 + quad * 8);
        a1r[kk] = *(const short8*)(SAd + (size_t)(wave * 32 + 16 + lm) * TCH + kk * 32 + quad * 8);
    }

    int ntS = (tid >> 6) & 3, qS = (tid >> 4) & 3, ccS = tid & 15;
    const __hip_bfloat16* srcB[3];
    #pragma unroll
    for (int t = 0; t < 3; ++t) {
        int col = (3 * g + t) * 64 + ntS * 16 + ccS;
        int colc = col < COLS ? col : COLS - 1;
        int bh = (colc * 241) >> 12;
        int c = colc - bh * 17;
        srcB[t] = Ub + ((size_t)bh * DM + d) * LTR + (size_t)c * TCH + qS * 8;
    }

    float4 rs0 = *(const float4*)(Rsh + (size_t)d * 128 + wave * 32 + quad * 4);
    float4 rs1 = *(const float4*)(Rsh + (size_t)d * 128 + wave * 32 + 16 + quad * 4);

    floatx4 acc[2][4];
    floatx4 zf = {0.f, 0.f, 0.f, 0.f};
    #pragma unroll
    for (int mi = 0; mi < 2; ++mi)
        #pragma unroll
        for (int nt = 0; nt < 4; ++nt) acc[mi][nt] = zf;

#define SG_STAGE(t_, kk0_, off_)                                              \
    {                                                                         \
        glds16(srcB[t_] + (kk0_) * 32,     (char*)Bs + (off_) + tid * 16);    \
        glds16(srcB[t_] + (kk0_ + 1) * 32, (char*)Bs + (off_) + 4096 + tid * 16); \
    }
#define SG_COMP(off_, kkA_)                                                   \
    {                                                                         \
        const short* bb_ = (const short*)((const char*)Bs + (off_));          \
        _Pragma("unroll")                                                     \
        for (int kk_ = 0; kk_ < 2; ++kk_) {                                   \
            _Pragma("unroll")                                                 \
            for (int nt_ = 0; nt_ < 4; ++nt_) {                               \
                short8 bv = *(const short8*)(bb_ + kk_ * 2048 + nt_ * 512 + lane * 8); \
                acc[0][nt_] = __builtin_amdgcn_mfma_f32_16x16x32_bf16(        \
                    a0r[(kkA_) + kk_], bv, acc[0][nt_], 0, 0, 0);             \
                acc[1][nt_] = __builtin_amdgcn_mfma_f32_16x16x32_bf16(        \
                    a1r[(kkA_) + kk_], bv, acc[1][nt_], 0, 0, 0);             \
            }                                                                 \
        }                                                                     \
    }
#define SG_EPI(cb_)                                                           \
    _Pragma("unroll")                                                         \
    for (int mi = 0; mi < 2; ++mi) {                                          \
        int row = wave * 32 + mi * 16 + quad * 4;                             \
        float4 rs = mi ? rs1 : rs0;                                           \
        _Pragma("unroll")                                                     \
        for (int nt_ = 0; nt_ < 4; ++nt_) {                                   \
            int col = (cb_) * 64 + nt_ * 16 + lm;                             \
            if (col < COLS) {                                                 \
                short4v o;                                                    \
                o[0] = bfs(acc[mi][nt_][0] + rs.x);                           \
                o[1] = bfs(acc[mi][nt_][1] + rs.y);                           \
                o[2] = bfs(acc[mi][nt_][2] + rs.z);                           \
                o[3] = bfs(acc[mi][nt_][3] + rs.w);                           \
                *(short4v*)(S + ((size_t)d * COLS + col) * TCH + row) = o;    \
            }                                                                 \
            acc[mi][nt_] = zf;                                                \
        }                                                                     \
    }

    SG_STAGE(0, 0, 0);
    SG_STAGE(0, 2, 8192);
    SG_STAGE(1, 0, 16384);
    BARV(4);
    SG_COMP(0, 0);
    BARV(2);
    SG_STAGE(1, 2, 0);
    SG_COMP(8192, 2);
    BARV(2);
    SG_STAGE(2, 0, 8192);
    SG_EPI(3 * g + 0);
    BARV(4);
    SG_COMP(16384, 0);
    BARV(2);
    SG_STAGE(2, 2, 16384);
    SG_COMP(0, 2);
    SG_EPI(3 * g + 1);
    BARV(2);
    SG_COMP(8192, 0);
    BARV(0);
    SG_COMP(16384, 2);
    SG_EPI(3 * g + 2);

#undef SG_STAGE
#undef SG_COMP
#undef SG_EPI
}

// ---------------------------------------------------------------------------
// 3c) carry scan over chunks (in place), loads prefetched up front
// ---------------------------------------------------------------------------
__global__ __launch_bounds__(64) void carry_kernel(
    __hip_bfloat16* __restrict__ SX,
    const float* __restrict__ log_dt,
    const float* __restrict__ A_re, const float* __restrict__ A_im,
    int layer) {
    int d = blockIdx.x, b = blockIdx.y;
    int n = threadIdx.x;
    float dt = expf(log_dt[layer * DM + d]);
    size_t ab = ((size_t)layer * DM + d) * DS + n;
    float Ar = A_re[ab], Ai = A_im[ab];
    float e = expf(dt * Ar);
    float wre = e * cosf(dt * Ai), wim = e * sinf(dt * Ai);
    #pragma unroll
    for (int t = 0; t < 7; ++t) {
        float r = wre * wre - wim * wim;
        wim = 2.0f * wre * wim; wre = r;
    }
    size_t base = ((size_t)d * COLS + (size_t)b * NC) * TCH + n;
    float sre[NC], sim[NC];
    #pragma unroll
    for (int c = 0; c < NC; ++c) {
        sre[c] = __bfloat162float(SX[base + (size_t)c * TCH]);
        sim[c] = __bfloat162float(SX[base + (size_t)c * TCH + 64]);
    }
    float xr = 0.0f, xi = 0.0f;
    #pragma unroll
    for (int c = 0; c < NC; ++c) {
        SX[base + (size_t)c * TCH]      = __float2bfloat16(xr);
        SX[base + (size_t)c * TCH + 64] = __float2bfloat16(xi);
        float nr = wre * xr - wim * xi + sre[c];
        xi = wre * xi + wim * xr + sim[c];
        xr = nr;
    }
}

// ---------------------------------------------------------------------------
// 3d) main chunk GEMM, 3 tiles per block, rotating 3x16KB LDS pipeline. (R5)
// ---------------------------------------------------------------------------
__global__ __launch_bounds__(256) void mainscan_kernel(
    const __hip_bfloat16* __restrict__ Ub, const __hip_bfloat16* __restrict__ X,
    const __hip_bfloat16* __restrict__ Abig, const float* __restrict__ T1sh,
    __hip_bfloat16* __restrict__ Ybt) {
    int id = blockIdx.x;               // 768 blocks
    int xcd = id & 7, j = id >> 3;     // j in [0,96)
    int dj = (j * 21846) >> 16;        // j/3
    int d = xcd * 32 + dj;
    int g = j - dj * 3;                // cb = 3g + t
    int tid = threadIdx.x, wave = tid >> 6, lane = tid & 63;
    int lm = lane & 15, quad = lane >> 4;
    const __hip_bfloat16* Ad = Abig + (size_t)d * TCH * 256;

    __shared__ short Bs[24576];        // 48 KB: 3 regions x 16 KB

    short8 a0r[8], a1r[8];
    #pragma unroll
    for (int kk = 0; kk < 8; ++kk) {
        a0r[kk] = *(const short8*)(Ad + (size_t)(wave * 32 + lm) * 256 + kk * 32 + quad * 8);
        a1r[kk] = *(const short8*)(Ad + (size_t)(wave * 32 + 16 + lm) * 256 + kk * 32 + quad * 8);
    }

    int ntS = (tid >> 6) & 3, qS = (tid >> 4) & 3, ccS = tid & 15;
    const __hip_bfloat16* srcU[3];
    const __hip_bfloat16* srcX[3];
    #pragma unroll
    for (int t = 0; t < 3; ++t) {
        int col = (3 * g + t) * 64 + ntS * 16 + ccS;
        int colc = col < COLS ? col : COLS - 1;
        int bh = (colc * 241) >> 12;
        int c = colc - bh * 17;
        srcU[t] = Ub + ((size_t)bh * DM + d) * LTR + (size_t)c * TCH + qS * 8;
        srcX[t] = X + ((size_t)d * COLS + colc) * TCH + qS * 8;
    }

    float4 t1a = *(const float4*)(T1sh + (size_t)d * 128 + wave * 32 + quad * 4);
    float4 t1b = *(const float4*)(T1sh + (size_t)d * 128 + wave * 32 + 16 + quad * 4);

    floatx4 acc[2][4];
    floatx4 zf = {0.f, 0.f, 0.f, 0.f};
    #pragma unroll
    for (int mi = 0; mi < 2; ++mi)
        #pragma unroll
        for (int nt = 0; nt < 4; ++nt) acc[mi][nt] = zf;

#define MS_STAGE_LO(t_, off_)                                                 \
    {                                                                         \
        _Pragma("unroll")                                                     \
        for (int k_ = 0; k_ < 4; ++k_)                                        \
            glds16(srcU[t_] + k_ * 32,                                        \
                   (char*)Bs + (off_) + k_ * 4096 + tid * 16);                \
    }
#define MS_STAGE_HI(t_, off_)                                                 \
    {                                                                         \
        _Pragma("unroll")                                                     \
        for (int k_ = 0; k_ < 4; ++k_)                                        \
            glds16(srcX[t_] + k_ * 32,                                        \
                   (char*)Bs + (off_) + k_ * 4096 + tid * 16);                \
    }
#define MS_COMP(off_, kkA_)                                                   \
    {                                                                         \
        const short* bb_ = (const short*)((const char*)Bs + (off_));          \
        _Pragma("unroll")                                                     \
        for (int kk_ = 0; kk_ < 4; ++kk_) {                                   \
            _Pragma("unroll")                                                 \
            for (int nt_ = 0; nt_ < 4; ++nt_) {                               \
                short8 bv = *(const short8*)(bb_ + kk_ * 2048 + nt_ * 512 + lane * 8); \
                acc[0][nt_] = __builtin_amdgcn_mfma_f32_16x16x32_bf16(        \
                    a0r[(kkA_) + kk_], bv, acc[0][nt_], 0, 0, 0);             \
                acc[1][nt_] = __builtin_amdgcn_mfma_f32_16x16x32_bf16(        \
                    a1r[(kkA_) + kk_], bv, acc[1][nt_], 0, 0, 0);             \
            }                                                                 \
        }                                                                     \
    }
#define MS_EPI(cb_)                                                           \
    _Pragma("unroll")                                                         \
    for (int mi = 0; mi < 2; ++mi) {                                          \
        int row0 = wave * 32 + mi * 16 + quad * 4;                            \
        float4 t1 = mi ? t1b : t1a;                                           \
        _Pragma("unroll")                                                     \
        for (int nt_ = 0; nt_ < 4; ++nt_) {                                   \
            int col = (cb_) * 64 + nt_ * 16 + lm;                             \
            if (col < COLS) {                                                 \
                int bh = (col * 241) >> 12;                                   \
                int c = col - bh * 17;                                        \
                int l0 = c * TCH + row0;                                      \
                float g0 = gelu_tanh(acc[mi][nt_][0] + t1.x);                 \
                float g1 = gelu_tanh(acc[mi][nt_][1] + t1.y);                 \
                float g2 = gelu_tanh(acc[mi][nt_][2] + t1.z);                 \
                float g3 = gelu_tanh(acc[mi][nt_][3] + t1.w);                 \
                __hip_bfloat16* dst = Ybt + ((size_t)bh * DM + d) * LTR + l0; \
                if (l0 + 3 < LT) {                                            \
                    short4v o;                                                \
                    o[0] = bfs(g0); o[1] = bfs(g1);                           \
                    o[2] = bfs(g2); o[3] = bfs(g3);                           \
                    *(short4v*)dst = o;                                       \
                } else {                                                      \
                    if (l0 + 0 < LT) dst[0] = __float2bfloat16(g0);           \
                    if (l0 + 1 < LT) dst[1] = __float2bfloat16(g1);           \
                    if (l0 + 2 < LT) dst[2] = __float2bfloat16(g2);           \
                    if (l0 + 3 < LT) dst[3] = __float2bfloat16(g3);           \
                }                                                             \
            }                                                                 \
            acc[mi][nt_] = zf;                                                \
        }                                                                     \
    }

    MS_STAGE_LO(0, 0);
    MS_STAGE_HI(0, 16384);
    MS_STAGE_LO(1, 32768);
    BARV(8);
    MS_COMP(0, 0);
    BARV(4);
    MS_STAGE_HI(1, 0);
    MS_COMP(16384, 4);
    BARV(4);
    MS_STAGE_LO(2, 16384);
    MS_EPI(3 * g + 0);
    BARV(8);
    MS_COMP(32768, 0);
    BARV(4);
    MS_STAGE_HI(2, 32768);
    MS_COMP(0, 4);
    MS_EPI(3 * g + 1);
    BARV(4);
    MS_COMP(16384, 0);
    BARV(0);
    MS_COMP(32768, 4);
    MS_EPI(3 * g + 2);

#undef MS_STAGE_LO
#undef MS_STAGE_HI
#undef MS_COMP
#undef MS_EPI
}

// ---------------------------------------------------------------------------
// 4) GEMM + GLU + residual + BN stats, transpose FUSED into A-staging.
//    R5 body (measured 55.7 us) with XCD-grouped grid: the 4 by-blocks
//    sharing one A-tile land on the SAME XCD slot (id%8) and adjacent in
//    dispatch order -> 3 of 4 A-tile reads become L2 hits.
//    id = 8*m + x: by = m&3, tile = x*68 + (m>>2)  (bijective: 2176=8*4*68).
// ---------------------------------------------------------------------------
__global__ __launch_bounds__(256) void gemm_glu_mfma_kernel(
    const __hip_bfloat16* __restrict__ Ybt, __hip_bfloat16* __restrict__ Ub,
    const __hip_bfloat16* __restrict__ Wtp, const float* __restrict__ out_b,
    const float* __restrict__ scsh, float* __restrict__ stats, int layer) {
    int id = blockIdx.x;               // 2176 blocks
    int x = id & 7, m = id >> 3;       // m in [0,272)
    int by = m & 3;
    int tile = x * 68 + (m >> 2);      // [0,544)
    int bq = (tile * 3856) >> 16;      // tile/17
    int bx = tile - bq * 17;
    int b = bq;
    int tid = threadIdx.x;
    int wave = tid >> 6, lane = tid & 63;
    int lm = lane & 15, quad = lane >> 4;
    int l0 = bx * 128;

    __shared__ short lds[16384];       // 32 KB: buf p at p*8192 (A 4096 + B 4096)

    const __hip_bfloat16* Wl = Wtp + (size_t)layer * 512 * 256 + (size_t)by * 128 * 256;

    // ---- A-staging mapping: thread = (kp in [0,16), l8 in [0,16)) ----
    int kp = tid >> 4;
    int l8 = tid & 15;
    const __hip_bfloat16* srcA = Ybt + ((size_t)b * DM + 2 * kp) * LTR + l0 + l8 * 8;
    int woff[8];
    {
        int qA = kp >> 2;
        #pragma unroll
        for (int jj = 0; jj < 8; ++jj) {
            int lloc = l8 * 8 + jj;
            int s4 = (qA + lloc + l8) & 3;      // (lloc>>3) == l8
            woff[jj] = lloc * 32 + s4 * 8 + (kp & 3) * 2;
        }
    }
    // ---- B-staging mapping (glds, inverse permutation) ----
    int rB_[2], qB_[2];
    #pragma unroll
    for (int i = 0; i < 2; ++i) {
        int u = i * 256 + tid;
        int r = u >> 2;
        rB_[i] = r;
        qB_[i] = ((u & 3) - r - (r >> 3)) & 3;
    }
    // ---- fragment read offsets (shorts) ----
    int aoff[4], boff[4];
    #pragma unroll
    for (int mi = 0; mi < 4; ++mi) {
        int r = (wave >> 1) * 64 + mi * 16 + lm;
        aoff[mi] = r * 32 + ((quad + r + (r >> 3)) & 3) * 8;
    }
    #pragma unroll
    for (int ni = 0; ni < 4; ++ni) {
        int r = (wave & 1) * 64 + ni * 16 + lm;
        boff[ni] = r * 32 + ((quad + r + (r >> 3)) & 3) * 8;
    }

    floatx4 acc[4][4];
    floatx4 zf = {0.f, 0.f, 0.f, 0.f};
    #pragma unroll
    for (int mi = 0; mi < 4; ++mi)
        #pragma unroll
        for (int ni = 0; ni < 4; ++ni) acc[mi][ni] = zf;

#define STAGE_B(S, P)                                                         \
    {                                                                         \
        char* bb_ = (char*)(lds + (P) * 8192 + 4096);                         \
        _Pragma("unroll")                                                     \
        for (int i_ = 0; i_ < 2; ++i_)                                        \
            glds16(Wl + (size_t)rB_[i_] * 256 + (S) * 32 + qB_[i_] * 8,       \
                   bb_ + (i_ * 256 + tid) * 16);                              \
    }
#define LOAD_A(S, G0, G1)                                                     \
    {                                                                         \
        const __hip_bfloat16* pa_ = srcA + (size_t)(S) * 32 * LTR;            \
        G0 = *(const short8*)pa_;                                             \
        G1 = *(const short8*)(pa_ + LTR);                                     \
    }
#define WRITE_A(P, G0, G1)                                                    \
    {                                                                         \
        short* ab_ = lds + (P) * 8192;                                        \
        _Pragma("unroll")                                                     \
        for (int j_ = 0; j_ < 8; ++j_) {                                      \
            unsigned pk_ = (unsigned)(unsigned short)G0[j_] |                 \
                           ((unsigned)(unsigned short)G1[j_] << 16);          \
            *(unsigned*)(ab_ + woff[j_]) = pk_;                               \
        }                                                                     \
    }
#define COMPUTE(P)                                                            \
    {                                                                         \
        const short* ab_ = lds + (P) * 8192;                                  \
        const short* bb_ = ab_ + 4096;                                        \
        short8 af_[4], bf_[4];                                                \
        _Pragma("unroll")                                                     \
        for (int mi_ = 0; mi_ < 4; ++mi_)                                     \
            af_[mi_] = *(const short8*)(ab_ + aoff[mi_]);                     \
        _Pragma("unroll")                                                     \
        for (int ni_ = 0; ni_ < 4; ++ni_)                                     \
            bf_[ni_] = *(const short8*)(bb_ + boff[ni_]);                     \
        _Pragma("unroll")                                                     \
        for (int mi_ = 0; mi_ < 4; ++mi_)                                     \
            _Pragma("unroll")                                                 \
            for (int ni_ = 0; ni_ < 4; ++ni_)                                 \
                acc[mi_][ni_] = __builtin_amdgcn_mfma_f32_16x16x32_bf16(      \
                    af_[mi_], bf_[ni_], acc[mi_][ni_], 0, 0, 0);              \
    }
#define FENCE2                                                                \
    asm volatile("s_waitcnt vmcnt(2)" ::: "memory");                          \
    asm volatile("s_waitcnt lgkmcnt(0)" ::: "memory");                        \
    __builtin_amdgcn_sched_barrier(0);                                        \
    __builtin_amdgcn_s_barrier();
#define FENCE0                                                                \
    asm volatile("s_waitcnt vmcnt(0)" ::: "memory");                          \
    asm volatile("s_waitcnt lgkmcnt(0)" ::: "memory");                        \
    __builtin_amdgcn_sched_barrier(0);                                        \
    __builtin_amdgcn_s_barrier();

    short8 gE0, gE1, gO0, gO1;
    // prologue: substep 0 into buf0, A(1) loads in flight
    STAGE_B(0, 0);
    LOAD_A(0, gE0, gE1);
    WRITE_A(0, gE0, gE1);          // compiler drains loads (and B0) here
    LOAD_A(1, gO0, gO1);
    asm volatile("s_waitcnt lgkmcnt(0)" ::: "memory");
    __builtin_amdgcn_sched_barrier(0);
    __builtin_amdgcn_s_barrier();

    // s=0
    STAGE_B(1, 1); COMPUTE(0); WRITE_A(1, gO0, gO1); LOAD_A(2, gE0, gE1); FENCE2;
    // s=1
    STAGE_B(2, 0); COMPUTE(1); WRITE_A(0, gE0, gE1); LOAD_A(3, gO0, gO1); FENCE2;
    // s=2
    STAGE_B(3, 1); COMPUTE(0); WRITE_A(1, gO0, gO1); LOAD_A(4, gE0, gE1); FENCE2;
    // s=3
    STAGE_B(4, 0); COMPUTE(1); WRITE_A(0, gE0, gE1); LOAD_A(5, gO0, gO1); FENCE2;
    // s=4
    STAGE_B(5, 1); COMPUTE(0); WRITE_A(1, gO0, gO1); LOAD_A(6, gE0, gE1); FENCE2;
    // s=5
    STAGE_B(6, 0); COMPUTE(1); WRITE_A(0, gE0, gE1); LOAD_A(7, gO0, gO1); FENCE2;
    // s=6
    STAGE_B(7, 1); COMPUTE(0); WRITE_A(1, gO0, gO1); FENCE0;
    // s=7
    COMPUTE(1);

#undef STAGE_B
#undef LOAD_A
#undef WRITE_A
#undef COMPUTE
#undef FENCE2
#undef FENCE0

    const float* bl = out_b + layer * 512;
    int Pbase = by * 64 + (wave & 1) * 32;
    int lw = l0 + (wave >> 1) * 64;
    #pragma unroll
    for (int ni = 0; ni < 2; ++ni) {
        int P = Pbase + ni * 16 + lm;
        float bz1 = bl[P], bz2 = bl[256 + P];
        float scP = scsh[P], shP = scsh[DM + P];
        __hip_bfloat16* ubrow = Ub + ((size_t)b * DM + P) * LTR;
        float sp = 0.f, sq = 0.f;
        #pragma unroll
        for (int mi = 0; mi < 4; ++mi) {
            int l0q = lw + mi * 16 + quad * 4;
            if (l0q >= LT) continue;
            floatx4 z1 = acc[mi][ni];
            floatx4 z2 = acc[mi][ni + 2];
            if (l0q + 4 <= LT) {
                short4v uv = *(const short4v*)(ubrow + l0q);
                float h0 = fmaf(scP, sbf(uv[0]), shP) + (z1[0] + bz1) * sigmoidf_(z2[0] + bz2);
                float h1 = fmaf(scP, sbf(uv[1]), shP) + (z1[1] + bz1) * sigmoidf_(z2[1] + bz2);
                float h2 = fmaf(scP, sbf(uv[2]), shP) + (z1[2] + bz1) * sigmoidf_(z2[2] + bz2);
                float h3 = fmaf(scP, sbf(uv[3]), shP) + (z1[3] + bz1) * sigmoidf_(z2[3] + bz2);
                short4v ov;
                ov[0] = bfs(h0); ov[1] = bfs(h1); ov[2] = bfs(h2); ov[3] = bfs(h3);
                *(short4v*)(ubrow + l0q) = ov;
                sp += (h0 + h1) + (h2 + h3);
                sq += (h0 * h0 + h1 * h1) + (h2 * h2 + h3 * h3);
            } else {
                #pragma unroll
                for (int r = 0; r < 4; ++r) {
                    int l = l0q + r;
                    if (l < LT) {
                        float uvv = __bfloat162float(ubrow[l]);
                        float hh = fmaf(scP, uvv, shP) + (z1[r] + bz1) * sigmoidf_(z2[r] + bz2);
                        ubrow[l] = __float2bfloat16(hh);
                        sp += hh; sq += hh * hh;
                    }
                }
            }
        }
        sp += __shfl_xor(sp, 16); sp += __shfl_xor(sp, 32);
        sq += __shfl_xor(sq, 16); sq += __shfl_xor(sq, 32);
        if (quad == 0) {
            atomicAdd(&stats[P], sp);
            atomicAdd(&stats[DM + P], sq);
        }
    }
}

// ---------------------------------------------------------------------------
// 5) final stats -> (sc, sh) for head
// ---------------------------------------------------------------------------
__global__ __launch_bounds__(256) void statsfin_kernel(
    const float* __restrict__ stats,
    const float* __restrict__ gamma, const float* __restrict__ beta,
    float* __restrict__ scsh, int layer) {
    int d = threadIdx.x;
    float s = stats[d], q = stats[DM + d];
    float mean = s * (1.0f / NTOT);
    float var  = q * (1.0f / NTOT) - mean * mean;
    float sc = rsqrtf(var + 1e-5f) * gamma[layer * DM + d];
    scsh[d] = sc;
    scsh[DM + d] = beta[layer * DM + d] - mean * sc;
}

// ---------------------------------------------------------------------------
// 6) head
// ---------------------------------------------------------------------------
__global__ __launch_bounds__(128) void head_kernel(
    const __hip_bfloat16* __restrict__ Ub, const float* __restrict__ scsh,
    const float* __restrict__ W1, const float* __restrict__ b1,
    const float* __restrict__ W2, const float* __restrict__ b2,
    float* __restrict__ out) {
    int hh = blockIdx.x;
    int b  = blockIdx.y;
    int j  = threadIdx.x;
    int l  = (L_ - 1) + hh;
    const __hip_bfloat16* urow = Ub + ((size_t)b * DM) * LTR + l;
    float a = b1[j];
    for (int k = 0; k < DM; ++k) {
        float hn = fmaf(scsh[k], __bfloat162float(urow[(size_t)k * LTR]), scsh[DM + k]);
        a = fmaf(hn, W1[k * 128 + j], a);
    }
    float hs = a * sigmoidf_(a);
    float v = hs * W2[j];
    v += __shfl_xor(v, 1);
    v += __shfl_xor(v, 2);
    v += __shfl_xor(v, 4);
    v += __shfl_xor(v, 8);
    v += __shfl_xor(v, 16);
    v += __shfl_xor(v, 32);
    __shared__ float partial[2];
    if ((j & 63) == 0) partial[j >> 6] = v;
    __syncthreads();
    if (j == 0) out[b * H_ + hh] = partial[0] + partial[1] + b2[0];
}

// ---------------------------------------------------------------------------
extern "C" void kernel_launch(void* const* d_in, const int* in_sizes, int n_in,
                              void* d_out, int out_size, void* d_ws, size_t ws_size,
                              hipStream_t stream) {
    (void)in_sizes; (void)n_in; (void)out_size; (void)ws_size;
    const float* x_past      = (const float*)d_in[0];
    const float* noisy       = (const float*)d_in[1];
    const float* t_in        = (const float*)d_in[2];
    const float* x_future    = (const float*)d_in[3];
    const float* static_attr = (const float*)d_in[4];
    const float* freqs       = (const float*)d_in[5];
    const float* phases      = (const float*)d_in[6];
    const float* in_W        = (const float*)d_in[7];
    const float* in_b        = (const float*)d_in[8];
    const float* tm_W1       = (const float*)d_in[9];
    const float* tm_b1       = (const float*)d_in[10];
    const float* tm_W2       = (const float*)d_in[11];
    const float* tm_b2       = (const float*)d_in[12];
    const float* log_dt      = (const float*)d_in[13];
    const float* A_re        = (const float*)d_in[14];
    const float* A_im        = (const float*)d_in[15];
    const float* C_re        = (const float*)d_in[16];
    const float* C_im        = (const float*)d_in[17];
    const float* Dp          = (const float*)d_in[18];
    const float* out_W       = (const float*)d_in[19];
    const float* out_b       = (const float*)d_in[20];
    const float* bn_gamma    = (const float*)d_in[21];
    const float* bn_beta     = (const float*)d_in[22];
    const float* head_W1     = (const float*)d_in[23];
    const float* head_b1     = (const float*)d_in[24];
    const float* head_W2     = (const float*)d_in[25];
    const float* head_b2     = (const float*)d_in[26];

    char* ws = (char*)d_ws;
    const size_t UB_OFF = 1u << 20;
    const size_t UB_BYT = (size_t)B_ * DM * LTR * 2;
    const size_t R1_OFF = UB_OFF + UB_BYT;
    const size_t RB     = (size_t)256 * COLS * TCH * 2;
    const size_t R2_OFF = R1_OFF + RB;
    const size_t AB_OFF = R2_OFF + RB;
    const size_t AB_BYT = (size_t)256 * TCH * 256 * 2;
    const size_t SA_OFF = AB_OFF + AB_BYT;
    const size_t SA_BYT = (size_t)256 * TCH * TCH * 2;
    const size_t WT_OFF = SA_OFF + SA_BYT;

    float*          tb    = (float*)(ws);
    float*          stats = (float*)(ws + (64 << 10));
    float*          scsh  = (float*)(ws + (96 << 10));
    float*          Rsh   = (float*)(ws + (128 << 10));
    float*          T1sh  = (float*)(ws + (256 << 10));
    __hip_bfloat16* Ub    = (__hip_bfloat16*)(ws + UB_OFF);
    __hip_bfloat16* R1    = (__hip_bfloat16*)(ws + R1_OFF);
    __hip_bfloat16* Ybt   = (__hip_bfloat16*)(ws + R2_OFF);
    __hip_bfloat16* Abig  = (__hip_bfloat16*)(ws + AB_OFF);
    __hip_bfloat16* SA    = (__hip_bfloat16*)(ws + SA_OFF);
    __hip_bfloat16* Wtp   = (__hip_bfloat16*)(ws + WT_OFF);

    time_mlp_kernel<<<dim3(B_), 256, 0, stream>>>(
        t_in, freqs, phases, tm_W1, tm_b1, tm_W2, tm_b2, tb);

    wt_prep_kernel<<<dim3(NL * 256), 256, 0, stream>>>(out_W, Wtp);

    input_proj_kernel<<<dim3(9, B_), 256, 0, stream>>>(
        x_past, noisy, x_future, static_attr, in_W, in_b, tb, Ub);

    for (int layer = 0; layer < NL; ++layer) {
        prep_kernel<<<dim3(256), 256, 0, stream>>>(
            log_dt, A_re, A_im, C_re, C_im, Dp, bn_gamma, bn_beta,
            stats, scsh, Abig, SA, Rsh, T1sh, layer);
        sgemm_kernel<<<dim3(768), 256, 0, stream>>>(Ub, SA, Rsh, R1);
        carry_kernel<<<dim3(256, B_), 64, 0, stream>>>(
            R1, log_dt, A_re, A_im, layer);
        mainscan_kernel<<<dim3(768), 256, 0, stream>>>(Ub, R1, Abig, T1sh, Ybt);
        gemm_glu_mfma_kernel<<<dim3(2176), 256, 0, stream>>>(
            Ybt, Ub, Wtp, out_b, scsh, stats, layer);
    }

    statsfin_kernel<<<dim3(1), 256, 0, stream>>>(
        stats, bn_gamma, bn_beta, scsh, NL - 1);

    head_kernel<<<dim3(H_, B_), 128, 0, stream>>>(
        Ub, scsh, head_W1, head_b1, head_W2, head_b2, (float*)d_out);
}

// Round 10
// 682.901 us; speedup vs baseline: 1.3337x; 1.0185x over previous
//
#include <hip/hip_runtime.h>
#include <hip/hip_bf16.h>
#include <math.h>

#define B_   32
#define L_   2048
#define H_   8
#define DMET 16
#define SDIM 27
#define DM   256
#define NL   4
#define DS   64
#define TE   256
#define LT   2055          // L + H - 1
#define LTR  2176          // 17*128: padded l for Ub/Ybt
#define TCH  128           // chunk length
#define NC   17            // chunks per sequence
#define COLS 544           // B_ * NC
#define NTOT (B_ * LT)

typedef __attribute__((ext_vector_type(8))) short short8;
typedef __attribute__((ext_vector_type(4))) short short4v;
typedef __attribute__((ext_vector_type(4))) float floatx4;

// fast sigmoid: 1/(1+2^(-x*log2 e)) via v_exp_f32 + v_rcp_f32.
__device__ __forceinline__ float sigmoidf_(float x) {
    float e = __builtin_amdgcn_exp2f(-1.4426950408889634f * x);
    return __builtin_amdgcn_rcpf(1.0f + e);
}

// tanh-gelu in sigmoid form: 0.5*(1+tanh(z)) == sigmoid(2z) exactly.
__device__ __forceinline__ float gelu_tanh(float x) {
    float inner = 1.5957691216057308f * fmaf(0.044715f * x * x, x, x);
    return x * sigmoidf_(inner);
}

// hardware exp/sin/cos (revolutions, fract-reduced).
__device__ __forceinline__ float fexp_(float x) {
    return __builtin_amdgcn_exp2f(1.4426950408889634f * x);
}
__device__ __forceinline__ float fsin_(float ph) {
    float r = ph * 0.15915494309189535f;
    r = r - floorf(r);
    return __builtin_amdgcn_sinf(r);
}
__device__ __forceinline__ float fcos_(float ph) {
    float r = ph * 0.15915494309189535f;
    r = r - floorf(r);
    return __builtin_amdgcn_cosf(r);
}

__device__ __forceinline__ short bfs(float x) {
    __hip_bfloat16 h = __float2bfloat16(x);
    return *(short*)&h;
}

__device__ __forceinline__ float sbf(short s) {
    unsigned u = ((unsigned)(unsigned short)s) << 16;
    return __uint_as_float(u);
}

__device__ __forceinline__ void glds16(const void* g, void* l) {
    __builtin_amdgcn_global_load_lds(
        (const __attribute__((address_space(1))) unsigned*)g,
        (__attribute__((address_space(3))) unsigned*)l, 16, 0, 0);
}

// counted-vmcnt fence + full barrier; lgkmcnt(0) drains this wave's ds ops
// so a later overwrite of the region is safe cross-wave.
#define BARV(n) do {                                                          \
    asm volatile("s_waitcnt vmcnt(" #n ") lgkmcnt(0)" ::: "memory");          \
    __builtin_amdgcn_s_barrier();                                             \
    asm volatile("" ::: "memory");                                            \
} while (0)

// ---------------------------------------------------------------------------
// 1) time MLP
// ---------------------------------------------------------------------------
__global__ __launch_bounds__(256) void time_mlp_kernel(
    const float* __restrict__ t, const float* __restrict__ freqs,
    const float* __restrict__ phases,
    const float* __restrict__ W1, const float* __restrict__ b1,
    const float* __restrict__ W2, const float* __restrict__ b2,
    float* __restrict__ tb) {
    int b = blockIdx.x;
    int tid = threadIdx.x;
    __shared__ float f[TE];
    __shared__ float hid[2 * TE];
    float tv = t[b];
    f[tid] = cosf(fmaf(tv, freqs[tid], phases[tid])) * 1.4142135623730951f;
    __syncthreads();
    float a0 = b1[tid], a1 = b1[tid + TE];
    for (int k = 0; k < TE; ++k) {
        float fk = f[k];
        a0 = fmaf(fk, W1[k * 2 * TE + tid], a0);
        a1 = fmaf(fk, W1[k * 2 * TE + tid + TE], a1);
    }
    hid[tid]      = a0 * sigmoidf_(a0);
    hid[tid + TE] = a1 * sigmoidf_(a1);
    __syncthreads();
    float acc = b2[tid];
    for (int j = 0; j < 2 * TE; ++j)
        acc = fmaf(hid[j], W2[j * DM + tid], acc);
    tb[b * DM + tid] = acc;
}

// ---------------------------------------------------------------------------
// 1b) out_W [NL][256][512] fp32 -> Wtp bf16 [NL][512 permuted cols][256 k]
// ---------------------------------------------------------------------------
__global__ __launch_bounds__(256) void wt_prep_kernel(
    const float* __restrict__ out_W, __hip_bfloat16* __restrict__ Wtp) {
    int bid = blockIdx.x;
    int layer = bid >> 8, k = bid & 255;
    int e = threadIdx.x;
    const float* src = out_W + ((size_t)layer * 256 + k) * 512;
    #pragma unroll
    for (int q = 0; q < 2; ++q) {
        int ee = e + q * 256;
        int P = ee & 255, half = ee >> 8;
        int by = P >> 6, pp = P & 63;
        int g = pp >> 5;
        int tcol = (pp & 31) + half * 32;
        int c = by * 128 + g * 64 + tcol;
        Wtp[((size_t)layer * 512 + c) * 256 + k] = __float2bfloat16(src[ee]);
    }
}

// ---------------------------------------------------------------------------
// 2) input projection -> Ub[b][d][l] bf16, zeroes pad
// ---------------------------------------------------------------------------
__global__ __launch_bounds__(256) void input_proj_kernel(
    const float* __restrict__ xp, const float* __restrict__ nf,
    const float* __restrict__ xf, const float* __restrict__ sa,
    const float* __restrict__ inW, const float* __restrict__ inb,
    const float* __restrict__ tb, __hip_bfloat16* __restrict__ Ub) {
    int b  = blockIdx.y;
    int l0 = blockIdx.x * 256;
    int tx = threadIdx.x;
    int l  = l0 + tx;

    __shared__ float feats[256][18];
    __shared__ float Ws[17][DM];
    __shared__ float sdot[DM];
    __shared__ float tbs[DM];
    __shared__ float sstat[SDIM];

    if (tx < SDIM) sstat[tx] = sa[b * SDIM + tx];
    for (int k = 0; k < 17; ++k) Ws[k][tx] = inW[k * DM + tx];
    tbs[tx] = tb[b * DM + tx];

    bool valid = (l < LT);
    if (valid) {
        const float* src = (l < L_) ? &xp[((size_t)b * L_ + l) * DMET]
                                    : &xf[((size_t)b * (H_ - 1) + (l - L_)) * DMET];
        #pragma unroll
        for (int k = 0; k < DMET; ++k) feats[tx][k] = src[k];
        feats[tx][16] = (l >= L_ - 1) ? nf[b * H_ + (l - (L_ - 1))] : 0.0f;
    }
    __syncthreads();

    float sd = 0.0f;
    for (int k = 0; k < SDIM; ++k)
        sd = fmaf(sstat[k], inW[(17 + k) * DM + tx], sd);
    sdot[tx] = sd;
    __syncthreads();

    if (l >= LTR) return;
    size_t baseb = ((size_t)b * DM) * LTR + l;
    if (!valid) {
        __hip_bfloat16 z = __float2bfloat16(0.0f);
        for (int d = 0; d < DM; ++d) Ub[baseb + (size_t)d * LTR] = z;
        return;
    }
    bool cond = (l >= L_ - 1);
    for (int d = 0; d < DM; ++d) {
        float acc = inb[d] + sdot[d] + (cond ? tbs[d] : 0.0f);
        #pragma unroll
        for (int k = 0; k < 17; ++k)
            acc = fmaf(feats[tx][k], Ws[k][d], acc);
        Ub[baseb + (size_t)d * LTR] = __float2bfloat16(acc);
    }
}

// ---------------------------------------------------------------------------
// 3a) per-layer per-channel matrix prep with BN folding + stats finalize
// ---------------------------------------------------------------------------
__global__ __launch_bounds__(256) void prep_kernel(
    const float* __restrict__ log_dt,
    const float* __restrict__ A_re, const float* __restrict__ A_im,
    const float* __restrict__ C_re, const float* __restrict__ C_im,
    const float* __restrict__ Dp,
    const float* __restrict__ gamma, const float* __restrict__ beta,
    float* __restrict__ stats, float* __restrict__ scsh,
    __hip_bfloat16* __restrict__ Abig, __hip_bfloat16* __restrict__ SA,
    float* __restrict__ Rsh, float* __restrict__ T1sh, int layer) {
    int d = blockIdx.x;
    int t = threadIdx.x;
    __shared__ float sAr[64], sAi[64], sCkr[64], sCki[64];
    __shared__ float kap[TCH];
    __shared__ float csum[TCH];
    __shared__ float s_sc, s_sh;

    if (t == 0) {
        float sc, sh;
        if (layer == 0) { sc = 1.0f; sh = 0.0f; }
        else {
            float s = stats[d], q = stats[DM + d];
            float mean = s * (1.0f / NTOT);
            float var  = q * (1.0f / NTOT) - mean * mean;
            sc = rsqrtf(var + 1e-5f) * gamma[(layer - 1) * DM + d];
            sh = beta[(layer - 1) * DM + d] - mean * sc;
        }
        s_sc = sc; s_sh = sh;
        scsh[d] = sc; scsh[DM + d] = sh;
        stats[d] = 0.0f; stats[DM + d] = 0.0f;
    }
    __syncthreads();
    float sc = s_sc, sh = s_sh;

    float dt = expf(log_dt[layer * DM + d]);
    float Dd = Dp[layer * DM + d];
    if (t < 64) {
        size_t ab = ((size_t)layer * DM + d) * DS + t;
        float Ar = A_re[ab], Ai = A_im[ab], Cr = C_re[ab], Ci = C_im[ab];
        float ar = dt * Ar, ai = dt * Ai;
        float e = expf(ar);
        float wre = e * cosf(ai), wim = e * sinf(ai);
        float mr = wre - 1.0f, mi = wim;
        float den = 1.0f / (Ar * Ar + Ai * Ai);
        float qr = (mr * Ar + mi * Ai) * den, qi = (mi * Ar - mr * Ai) * den;
        sCkr[t] = Cr * qr - Ci * qi;
        sCki[t] = Cr * qi + Ci * qr;
        sAr[t] = ar;
        sAi[t] = ai;
        float s2 = sinf(0.5f * ai);
        float dr = fmaf(expm1f(ar), cosf(ai), -2.0f * s2 * s2);
        float di = e * sinf(ai);
        float a128 = 128.0f * ar, b128 = 128.0f * ai;
        float s2b = sinf(0.5f * b128);
        float nr = fmaf(expm1f(a128), cosf(b128), -2.0f * s2b * s2b);
        float ni = expf(a128) * sinf(b128);
        float dd2 = 1.0f / (dr * dr + di * di);
        float gr = (nr * dr + ni * di) * dd2;
        float gi = (ni * dr - nr * di) * dd2;
        Rsh[(size_t)d * 128 + t]      = sh * gr;
        Rsh[(size_t)d * 128 + 64 + t] = sh * gi;
    }
    __syncthreads();

    {
        int delta = t >> 1, half = t & 1;
        float fd = (float)delta;
        float p = 0.0f;
        #pragma unroll 8
        for (int n = half * 32; n < half * 32 + 32; ++n) {
            float er = fexp_(fd * sAr[n]);
            float ph = fd * sAi[n];
            p += er * (sCkr[n] * fcos_(ph) - sCki[n] * fsin_(ph));
        }
        p += __shfl_xor(p, 1);
        if (half == 0) kap[delta] = 2.0f * p + (delta == 0 ? Dd : 0.0f);
    }
    __syncthreads();

    if (t < 128) csum[t] = kap[t];
    __syncthreads();
    for (int off = 1; off < 128; off <<= 1) {
        float v = 0.0f;
        if (t >= off && t < 128) v = csum[t - off];
        __syncthreads();
        if (t < 128) csum[t] += v;
        __syncthreads();
    }
    if (t < 128) T1sh[(size_t)d * 128 + t] = sh * csum[t];

    __hip_bfloat16* Ad = Abig + (size_t)d * TCH * 256;
    for (int idx = t; idx < TCH * TCH; idx += 256) {
        int i = idx >> 7, m = idx & 127;
        Ad[(size_t)i * 256 + m] = __float2bfloat16(m <= i ? sc * kap[i - m] : 0.0f);
    }
    for (int idx = t; idx < TCH * 64; idx += 256) {
        int i = idx >> 6, n = idx & 63;
        float fp = (float)(i + 1);
        float er = fexp_(fp * sAr[n]);
        float ph = fp * sAi[n];
        float c = fcos_(ph), s = fsin_(ph);
        float vr = er * (sCkr[n] * c - sCki[n] * s);
        float vi = er * (sCkr[n] * s + sCki[n] * c);
        Ad[(size_t)i * 256 + 128 + n] = __float2bfloat16(2.0f * vr);
        Ad[(size_t)i * 256 + 192 + n] = __float2bfloat16(-2.0f * vi);
    }
    __hip_bfloat16* Sd = SA + (size_t)d * TCH * TCH;
    for (int idx = t; idx < 64 * TCH; idx += 256) {
        int n = idx >> 7, m = idx & 127;
        float fp = (float)(127 - m);
        float er = sc * fexp_(fp * sAr[n]);
        float ph = fp * sAi[n];
        Sd[(size_t)n * 128 + m]        = __float2bfloat16(er * fcos_(ph));
        Sd[(size_t)(64 + n) * 128 + m] = __float2bfloat16(er * fsin_(ph));
    }
}

// ---------------------------------------------------------------------------
// 3b) S-GEMM, 3 tiles per block, rotating 3-region LDS pipeline. (R5)
//     T5: s_setprio(1) around MFMA clusters.
// ---------------------------------------------------------------------------
__global__ __launch_bounds__(256) void sgemm_kernel(
    const __hip_bfloat16* __restrict__ Ub, const __hip_bfloat16* __restrict__ SA,
    const float* __restrict__ Rsh, __hip_bfloat16* __restrict__ S) {
    int id = blockIdx.x;               // 768 blocks
    int xcd = id & 7, j = id >> 3;     // j in [0,96)
    int dj = (j * 21846) >> 16;        // j/3
    int d = xcd * 32 + dj;
    int g = j - dj * 3;                // cb group: cb = 3g + t
    int tid = threadIdx.x, wave = tid >> 6, lane = tid & 63;
    int lm = lane & 15, quad = lane >> 4;
    const __hip_bfloat16* SAd = SA + (size_t)d * TCH * TCH;

    __shared__ short Bs[12288];        // 24 KB: 3 regions x 8 KB

    short8 a0r[4], a1r[4];
    #pragma unroll
    for (int kk = 0; kk < 4; ++kk) {
        a0r[kk] = *(const short8*)(SAd + (size_t)(wave * 32 + lm) * TCH + kk * 32 + quad * 8);
        a1r[kk] = *(const short8*)(SAd + (size_t)(wave * 32 + 16 + lm) * TCH + kk * 32 + quad * 8);
    }

    int ntS = (tid >> 6) & 3, qS = (tid >> 4) & 3, ccS = tid & 15;
    const __hip_bfloat16* srcB[3];
    #pragma unroll
    for (int t = 0; t < 3; ++t) {
        int col = (3 * g + t) * 64 + ntS * 16 + ccS;
        int colc = col < COLS ? col : COLS - 1;
        int bh = (colc * 241) >> 12;
        int c = colc - bh * 17;
        srcB[t] = Ub + ((size_t)bh * DM + d) * LTR + (size_t)c * TCH + qS * 8;
    }

    float4 rs0 = *(const float4*)(Rsh + (size_t)d * 128 + wave * 32 + quad * 4);
    float4 rs1 = *(const float4*)(Rsh + (size_t)d * 128 + wave * 32 + 16 + quad * 4);

    floatx4 acc[2][4];
    floatx4 zf = {0.f, 0.f, 0.f, 0.f};
    #pragma unroll
    for (int mi = 0; mi < 2; ++mi)
        #pragma unroll
        for (int nt = 0; nt < 4; ++nt) acc[mi][nt] = zf;

#define SG_STAGE(t_, kk0_, off_)                                              \
    {                                                                         \
        glds16(srcB[t_] + (kk0_) * 32,     (char*)Bs + (off_) + tid * 16);    \
        glds16(srcB[t_] + (kk0_ + 1) * 32, (char*)Bs + (off_) + 4096 + tid * 16); \
    }
#define SG_COMP(off_, kkA_)                                                   \
    {                                                                         \
        const short* bb_ = (const short*)((const char*)Bs + (off_));          \
        __builtin_amdgcn_s_setprio(1);                                        \
        _Pragma("unroll")                                                     \
        for (int kk_ = 0; kk_ < 2; ++kk_) {                                   \
            _Pragma("unroll")                                                 \
            for (int nt_ = 0; nt_ < 4; ++nt_) {                               \
                short8 bv = *(const short8*)(bb_ + kk_ * 2048 + nt_ * 512 + lane * 8); \
                acc[0][nt_] = __builtin_amdgcn_mfma_f32_16x16x32_bf16(        \
                    a0r[(kkA_) + kk_], bv, acc[0][nt_], 0, 0, 0);             \
                acc[1][nt_] = __builtin_amdgcn_mfma_f32_16x16x32_bf16(        \
                    a1r[(kkA_) + kk_], bv, acc[1][nt_], 0, 0, 0);             \
            }                                                                 \
        }                                                                     \
        __builtin_amdgcn_s_setprio(0);                                        \
    }
#define SG_EPI(cb_)                                                           \
    _Pragma("unroll")                                                         \
    for (int mi = 0; mi < 2; ++mi) {                                          \
        int row = wave * 32 + mi * 16 + quad * 4;                             \
        float4 rs = mi ? rs1 : rs0;                                           \
        _Pragma("unroll")                                                     \
        for (int nt_ = 0; nt_ < 4; ++nt_) {                                   \
            int col = (cb_) * 64 + nt_ * 16 + lm;                             \
            if (col < COLS) {                                                 \
                short4v o;                                                    \
                o[0] = bfs(acc[mi][nt_][0] + rs.x);                           \
                o[1] = bfs(acc[mi][nt_][1] + rs.y);                           \
                o[2] = bfs(acc[mi][nt_][2] + rs.z);                           \
                o[3] = bfs(acc[mi][nt_][3] + rs.w);                           \
                *(short4v*)(S + ((size_t)d * COLS + col) * TCH + row) = o;    \
            }                                                                 \
            acc[mi][nt_] = zf;                                                \
        }                                                                     \
    }

    SG_STAGE(0, 0, 0);
    SG_STAGE(0, 2, 8192);
    SG_STAGE(1, 0, 16384);
    BARV(4);
    SG_COMP(0, 0);
    BARV(2);
    SG_STAGE(1, 2, 0);
    SG_COMP(8192, 2);
    BARV(2);
    SG_STAGE(2, 0, 8192);
    SG_EPI(3 * g + 0);
    BARV(4);
    SG_COMP(16384, 0);
    BARV(2);
    SG_STAGE(2, 2, 16384);
    SG_COMP(0, 2);
    SG_EPI(3 * g + 1);
    BARV(2);
    SG_COMP(8192, 0);
    BARV(0);
    SG_COMP(16384, 2);
    SG_EPI(3 * g + 2);

#undef SG_STAGE
#undef SG_COMP
#undef SG_EPI
}

// ---------------------------------------------------------------------------
// 3c) carry scan over chunks (in place), loads prefetched up front
// ---------------------------------------------------------------------------
__global__ __launch_bounds__(64) void carry_kernel(
    __hip_bfloat16* __restrict__ SX,
    const float* __restrict__ log_dt,
    const float* __restrict__ A_re, const float* __restrict__ A_im,
    int layer) {
    int d = blockIdx.x, b = blockIdx.y;
    int n = threadIdx.x;
    float dt = expf(log_dt[layer * DM + d]);
    size_t ab = ((size_t)layer * DM + d) * DS + n;
    float Ar = A_re[ab], Ai = A_im[ab];
    float e = expf(dt * Ar);
    float wre = e * cosf(dt * Ai), wim = e * sinf(dt * Ai);
    #pragma unroll
    for (int t = 0; t < 7; ++t) {
        float r = wre * wre - wim * wim;
        wim = 2.0f * wre * wim; wre = r;
    }
    size_t base = ((size_t)d * COLS + (size_t)b * NC) * TCH + n;
    float sre[NC], sim[NC];
    #pragma unroll
    for (int c = 0; c < NC; ++c) {
        sre[c] = __bfloat162float(SX[base + (size_t)c * TCH]);
        sim[c] = __bfloat162float(SX[base + (size_t)c * TCH + 64]);
    }
    float xr = 0.0f, xi = 0.0f;
    #pragma unroll
    for (int c = 0; c < NC; ++c) {
        SX[base + (size_t)c * TCH]      = __float2bfloat16(xr);
        SX[base + (size_t)c * TCH + 64] = __float2bfloat16(xi);
        float nr = wre * xr - wim * xi + sre[c];
        xi = wre * xi + wim * xr + sim[c];
        xr = nr;
    }
}

// ---------------------------------------------------------------------------
// 3d) main chunk GEMM, 3 tiles per block, rotating 3x16KB LDS pipeline. (R5)
//     T5: s_setprio(1) around MFMA clusters.
// ---------------------------------------------------------------------------
__global__ __launch_bounds__(256) void mainscan_kernel(
    const __hip_bfloat16* __restrict__ Ub, const __hip_bfloat16* __restrict__ X,
    const __hip_bfloat16* __restrict__ Abig, const float* __restrict__ T1sh,
    __hip_bfloat16* __restrict__ Ybt) {
    int id = blockIdx.x;               // 768 blocks
    int xcd = id & 7, j = id >> 3;     // j in [0,96)
    int dj = (j * 21846) >> 16;        // j/3
    int d = xcd * 32 + dj;
    int g = j - dj * 3;                // cb = 3g + t
    int tid = threadIdx.x, wave = tid >> 6, lane = tid & 63;
    int lm = lane & 15, quad = lane >> 4;
    const __hip_bfloat16* Ad = Abig + (size_t)d * TCH * 256;

    __shared__ short Bs[24576];        // 48 KB: 3 regions x 16 KB

    short8 a0r[8], a1r[8];
    #pragma unroll
    for (int kk = 0; kk < 8; ++kk) {
        a0r[kk] = *(const short8*)(Ad + (size_t)(wave * 32 + lm) * 256 + kk * 32 + quad * 8);
        a1r[kk] = *(const short8*)(Ad + (size_t)(wave * 32 + 16 + lm) * 256 + kk * 32 + quad * 8);
    }

    int ntS = (tid >> 6) & 3, qS = (tid >> 4) & 3, ccS = tid & 15;
    const __hip_bfloat16* srcU[3];
    const __hip_bfloat16* srcX[3];
    #pragma unroll
    for (int t = 0; t < 3; ++t) {
        int col = (3 * g + t) * 64 + ntS * 16 + ccS;
        int colc = col < COLS ? col : COLS - 1;
        int bh = (colc * 241) >> 12;
        int c = colc - bh * 17;
        srcU[t] = Ub + ((size_t)bh * DM + d) * LTR + (size_t)c * TCH + qS * 8;
        srcX[t] = X + ((size_t)d * COLS + colc) * TCH + qS * 8;
    }

    float4 t1a = *(const float4*)(T1sh + (size_t)d * 128 + wave * 32 + quad * 4);
    float4 t1b = *(const float4*)(T1sh + (size_t)d * 128 + wave * 32 + 16 + quad * 4);

    floatx4 acc[2][4];
    floatx4 zf = {0.f, 0.f, 0.f, 0.f};
    #pragma unroll
    for (int mi = 0; mi < 2; ++mi)
        #pragma unroll
        for (int nt = 0; nt < 4; ++nt) acc[mi][nt] = zf;

#define MS_STAGE_LO(t_, off_)                                                 \
    {                                                                         \
        _Pragma("unroll")                                                     \
        for (int k_ = 0; k_ < 4; ++k_)                                        \
            glds16(srcU[t_] + k_ * 32,                                        \
                   (char*)Bs + (off_) + k_ * 4096 + tid * 16);                \
    }
#define MS_STAGE_HI(t_, off_)                                                 \
    {                                                                         \
        _Pragma("unroll")                                                     \
        for (int k_ = 0; k_ < 4; ++k_)                                        \
            glds16(srcX[t_] + k_ * 32,                                        \
                   (char*)Bs + (off_) + k_ * 4096 + tid * 16);                \
    }
#define MS_COMP(off_, kkA_)                                                   \
    {                                                                         \
        const short* bb_ = (const short*)((const char*)Bs + (off_));          \
        __builtin_amdgcn_s_setprio(1);                                        \
        _Pragma("unroll")                                                     \
        for (int kk_ = 0; kk_ < 4; ++kk_) {                                   \
            _Pragma("unroll")                                                 \
            for (int nt_ = 0; nt_ < 4; ++nt_) {                               \
                short8 bv = *(const short8*)(bb_ + kk_ * 2048 + nt_ * 512 + lane * 8); \
                acc[0][nt_] = __builtin_amdgcn_mfma_f32_16x16x32_bf16(        \
                    a0r[(kkA_) + kk_], bv, acc[0][nt_], 0, 0, 0);             \
                acc[1][nt_] = __builtin_amdgcn_mfma_f32_16x16x32_bf16(        \
                    a1r[(kkA_) + kk_], bv, acc[1][nt_], 0, 0, 0);             \
            }                                                                 \
        }                                                                     \
        __builtin_amdgcn_s_setprio(0);                                        \
    }
#define MS_EPI(cb_)                                                           \
    _Pragma("unroll")                                                         \
    for (int mi = 0; mi < 2; ++mi) {                                          \
        int row0 = wave * 32 + mi * 16 + quad * 4;                            \
        float4 t1 = mi ? t1b : t1a;                                           \
        _Pragma("unroll")                                                     \
        for (int nt_ = 0; nt_ < 4; ++nt_) {                                   \
            int col = (cb_) * 64 + nt_ * 16 + lm;                             \
            if (col < COLS) {                                                 \
                int bh = (col * 241) >> 12;                                   \
                int c = col - bh * 17;                                        \
                int l0 = c * TCH + row0;                                      \
                float g0 = gelu_tanh(acc[mi][nt_][0] + t1.x);                 \
                float g1 = gelu_tanh(acc[mi][nt_][1] + t1.y);                 \
                float g2 = gelu_tanh(acc[mi][nt_][2] + t1.z);                 \
                float g3 = gelu_tanh(acc[mi][nt_][3] + t1.w);                 \
                __hip_bfloat16* dst = Ybt + ((size_t)bh * DM + d) * LTR + l0; \
                if (l0 + 3 < LT) {                                            \
                    short4v o;                                                \
                    o[0] = bfs(g0); o[1] = bfs(g1);                           \
                    o[2] = bfs(g2); o[3] = bfs(g3);                           \
                    *(short4v*)dst = o;                                       \
                } else {                                                      \
                    if (l0 + 0 < LT) dst[0] = __float2bfloat16(g0);           \
                    if (l0 + 1 < LT) dst[1] = __float2bfloat16(g1);           \
                    if (l0 + 2 < LT) dst[2] = __float2bfloat16(g2);           \
                    if (l0 + 3 < LT) dst[3] = __float2bfloat16(g3);           \
                }                                                             \
            }                                                                 \
            acc[mi][nt_] = zf;                                                \
        }                                                                     \
    }

    MS_STAGE_LO(0, 0);
    MS_STAGE_HI(0, 16384);
    MS_STAGE_LO(1, 32768);
    BARV(8);
    MS_COMP(0, 0);
    BARV(4);
    MS_STAGE_HI(1, 0);
    MS_COMP(16384, 4);
    BARV(4);
    MS_STAGE_LO(2, 16384);
    MS_EPI(3 * g + 0);
    BARV(8);
    MS_COMP(32768, 0);
    BARV(4);
    MS_STAGE_HI(2, 32768);
    MS_COMP(0, 4);
    MS_EPI(3 * g + 1);
    BARV(4);
    MS_COMP(16384, 0);
    BARV(0);
    MS_COMP(32768, 4);
    MS_EPI(3 * g + 2);

#undef MS_STAGE_LO
#undef MS_STAGE_HI
#undef MS_COMP
#undef MS_EPI
}

// ---------------------------------------------------------------------------
// 4) GEMM + GLU + residual + BN stats, transpose FUSED into A-staging.
//    R9 grid (XCD-grouped A-tile reuse) + T5 setprio around MFMA clusters.
//    id = 8*m + x: by = m&3, tile = x*68 + (m>>2)  (bijective: 2176=8*4*68).
// ---------------------------------------------------------------------------
__global__ __launch_bounds__(256) void gemm_glu_mfma_kernel(
    const __hip_bfloat16* __restrict__ Ybt, __hip_bfloat16* __restrict__ Ub,
    const __hip_bfloat16* __restrict__ Wtp, const float* __restrict__ out_b,
    const float* __restrict__ scsh, float* __restrict__ stats, int layer) {
    int id = blockIdx.x;               // 2176 blocks
    int x = id & 7, m = id >> 3;       // m in [0,272)
    int by = m & 3;
    int tile = x * 68 + (m >> 2);      // [0,544)
    int bq = (tile * 3856) >> 16;      // tile/17
    int bx = tile - bq * 17;
    int b = bq;
    int tid = threadIdx.x;
    int wave = tid >> 6, lane = tid & 63;
    int lm = lane & 15, quad = lane >> 4;
    int l0 = bx * 128;

    __shared__ short lds[16384];       // 32 KB: buf p at p*8192 (A 4096 + B 4096)

    const __hip_bfloat16* Wl = Wtp + (size_t)layer * 512 * 256 + (size_t)by * 128 * 256;

    // ---- A-staging mapping: thread = (kp in [0,16), l8 in [0,16)) ----
    int kp = tid >> 4;
    int l8 = tid & 15;
    const __hip_bfloat16* srcA = Ybt + ((size_t)b * DM + 2 * kp) * LTR + l0 + l8 * 8;
    int woff[8];
    {
        int qA = kp >> 2;
        #pragma unroll
        for (int jj = 0; jj < 8; ++jj) {
            int lloc = l8 * 8 + jj;
            int s4 = (qA + lloc + l8) & 3;      // (lloc>>3) == l8
            woff[jj] = lloc * 32 + s4 * 8 + (kp & 3) * 2;
        }
    }
    // ---- B-staging mapping (glds, inverse permutation) ----
    int rB_[2], qB_[2];
    #pragma unroll
    for (int i = 0; i < 2; ++i) {
        int u = i * 256 + tid;
        int r = u >> 2;
        rB_[i] = r;
        qB_[i] = ((u & 3) - r - (r >> 3)) & 3;
    }
    // ---- fragment read offsets (shorts) ----
    int aoff[4], boff[4];
    #pragma unroll
    for (int mi = 0; mi < 4; ++mi) {
        int r = (wave >> 1) * 64 + mi * 16 + lm;
        aoff[mi] = r * 32 + ((quad + r + (r >> 3)) & 3) * 8;
    }
    #pragma unroll
    for (int ni = 0; ni < 4; ++ni) {
        int r = (wave & 1) * 64 + ni * 16 + lm;
        boff[ni] = r * 32 + ((quad + r + (r >> 3)) & 3) * 8;
    }

    floatx4 acc[4][4];
    floatx4 zf = {0.f, 0.f, 0.f, 0.f};
    #pragma unroll
    for (int mi = 0; mi < 4; ++mi)
        #pragma unroll
        for (int ni = 0; ni < 4; ++ni) acc[mi][ni] = zf;

#define STAGE_B(S, P)                                                         \
    {                                                                         \
        char* bb_ = (char*)(lds + (P) * 8192 + 4096);                         \
        _Pragma("unroll")                                                     \
        for (int i_ = 0; i_ < 2; ++i_)                                        \
            glds16(Wl + (size_t)rB_[i_] * 256 + (S) * 32 + qB_[i_] * 8,       \
                   bb_ + (i_ * 256 + tid) * 16);                              \
    }
#define LOAD_A(S, G0, G1)                                                     \
    {                                                                         \
        const __hip_bfloat16* pa_ = srcA + (size_t)(S) * 32 * LTR;            \
        G0 = *(const short8*)pa_;                                             \
        G1 = *(const short8*)(pa_ + LTR);                                     \
    }
#define WRITE_A(P, G0, G1)                                                    \
    {                                                                         \
        short* ab_ = lds + (P) * 8192;                                        \
        _Pragma("unroll")                                                     \
        for (int j_ = 0; j_ < 8; ++j_) {                                      \
            unsigned pk_ = (unsigned)(unsigned short)G0[j_] |                 \
                           ((unsigned)(unsigned short)G1[j_] << 16);          \
            *(unsigned*)(ab_ + woff[j_]) = pk_;                               \
        }                                                                     \
    }
#define COMPUTE(P)                                                            \
    {                                                                         \
        const short* ab_ = lds + (P) * 8192;                                  \
        const short* bb_ = ab_ + 4096;                                        \
        short8 af_[4], bf_[4];                                                \
        _Pragma("unroll")                                                     \
        for (int mi_ = 0; mi_ < 4; ++mi_)                                     \
            af_[mi_] = *(const short8*)(ab_ + aoff[mi_]);                     \
        _Pragma("unroll")                                                     \
        for (int ni_ = 0; ni_ < 4; ++ni_)                                     \
            bf_[ni_] = *(const short8*)(bb_ + boff[ni_]);                     \
        __builtin_amdgcn_s_setprio(1);                                        \
        _Pragma("unroll")                                                     \
        for (int mi_ = 0; mi_ < 4; ++mi_)                                     \
            _Pragma("unroll")                                                 \
            for (int ni_ = 0; ni_ < 4; ++ni_)                                 \
                acc[mi_][ni_] = __builtin_amdgcn_mfma_f32_16x16x32_bf16(      \
                    af_[mi_], bf_[ni_], acc[mi_][ni_], 0, 0, 0);              \
        __builtin_amdgcn_s_setprio(0);                                        \
    }
#define FENCE2                                                                \
    asm volatile("s_waitcnt vmcnt(2)" ::: "memory");                          \
    asm volatile("s_waitcnt lgkmcnt(0)" ::: "memory");                        \
    __builtin_amdgcn_sched_barrier(0);                                        \
    __builtin_amdgcn_s_barrier();
#define FENCE0                                                                \
    asm volatile("s_waitcnt vmcnt(0)" ::: "memory");                          \
    asm volatile("s_waitcnt lgkmcnt(0)" ::: "memory");                        \
    __builtin_amdgcn_sched_barrier(0);                                        \
    __builtin_amdgcn_s_barrier();

    short8 gE0, gE1, gO0, gO1;
    // prologue: substep 0 into buf0, A(1) loads in flight
    STAGE_B(0, 0);
    LOAD_A(0, gE0, gE1);
    WRITE_A(0, gE0, gE1);          // compiler drains loads (and B0) here
    LOAD_A(1, gO0, gO1);
    asm volatile("s_waitcnt lgkmcnt(0)" ::: "memory");
    __builtin_amdgcn_sched_barrier(0);
    __builtin_amdgcn_s_barrier();

    // s=0
    STAGE_B(1, 1); COMPUTE(0); WRITE_A(1, gO0, gO1); LOAD_A(2, gE0, gE1); FENCE2;
    // s=1
    STAGE_B(2, 0); COMPUTE(1); WRITE_A(0, gE0, gE1); LOAD_A(3, gO0, gO1); FENCE2;
    // s=2
    STAGE_B(3, 1); COMPUTE(0); WRITE_A(1, gO0, gO1); LOAD_A(4, gE0, gE1); FENCE2;
    // s=3
    STAGE_B(4, 0); COMPUTE(1); WRITE_A(0, gE0, gE1); LOAD_A(5, gO0, gO1); FENCE2;
    // s=4
    STAGE_B(5, 1); COMPUTE(0); WRITE_A(1, gO0, gO1); LOAD_A(6, gE0, gE1); FENCE2;
    // s=5
    STAGE_B(6, 0); COMPUTE(1); WRITE_A(0, gE0, gE1); LOAD_A(7, gO0, gO1); FENCE2;
    // s=6
    STAGE_B(7, 1); COMPUTE(0); WRITE_A(1, gO0, gO1); FENCE0;
    // s=7
    COMPUTE(1);

#undef STAGE_B
#undef LOAD_A
#undef WRITE_A
#undef COMPUTE
#undef FENCE2
#undef FENCE0

    const float* bl = out_b + layer * 512;
    int Pbase = by * 64 + (wave & 1) * 32;
    int lw = l0 + (wave >> 1) * 64;
    #pragma unroll
    for (int ni = 0; ni < 2; ++ni) {
        int P = Pbase + ni * 16 + lm;
        float bz1 = bl[P], bz2 = bl[256 + P];
        float scP = scsh[P], shP = scsh[DM + P];
        __hip_bfloat16* ubrow = Ub + ((size_t)b * DM + P) * LTR;
        float sp = 0.f, sq = 0.f;
        #pragma unroll
        for (int mi = 0; mi < 4; ++mi) {
            int l0q = lw + mi * 16 + quad * 4;
            if (l0q >= LT) continue;
            floatx4 z1 = acc[mi][ni];
            floatx4 z2 = acc[mi][ni + 2];
            if (l0q + 4 <= LT) {
                short4v uv = *(const short4v*)(ubrow + l0q);
                float h0 = fmaf(scP, sbf(uv[0]), shP) + (z1[0] + bz1) * sigmoidf_(z2[0] + bz2);
                float h1 = fmaf(scP, sbf(uv[1]), shP) + (z1[1] + bz1) * sigmoidf_(z2[1] + bz2);
                float h2 = fmaf(scP, sbf(uv[2]), shP) + (z1[2] + bz1) * sigmoidf_(z2[2] + bz2);
                float h3 = fmaf(scP, sbf(uv[3]), shP) + (z1[3] + bz1) * sigmoidf_(z2[3] + bz2);
                short4v ov;
                ov[0] = bfs(h0); ov[1] = bfs(h1); ov[2] = bfs(h2); ov[3] = bfs(h3);
                *(short4v*)(ubrow + l0q) = ov;
                sp += (h0 + h1) + (h2 + h3);
                sq += (h0 * h0 + h1 * h1) + (h2 * h2 + h3 * h3);
            } else {
                #pragma unroll
                for (int r = 0; r < 4; ++r) {
                    int l = l0q + r;
                    if (l < LT) {
                        float uvv = __bfloat162float(ubrow[l]);
                        float hh = fmaf(scP, uvv, shP) + (z1[r] + bz1) * sigmoidf_(z2[r] + bz2);
                        ubrow[l] = __float2bfloat16(hh);
                        sp += hh; sq += hh * hh;
                    }
                }
            }
        }
        sp += __shfl_xor(sp, 16); sp += __shfl_xor(sp, 32);
        sq += __shfl_xor(sq, 16); sq += __shfl_xor(sq, 32);
        if (quad == 0) {
            atomicAdd(&stats[P], sp);
            atomicAdd(&stats[DM + P], sq);
        }
    }
}

// ---------------------------------------------------------------------------
// 5) final stats -> (sc, sh) for head
// ---------------------------------------------------------------------------
__global__ __launch_bounds__(256) void statsfin_kernel(
    const float* __restrict__ stats,
    const float* __restrict__ gamma, const float* __restrict__ beta,
    float* __restrict__ scsh, int layer) {
    int d = threadIdx.x;
    float s = stats[d], q = stats[DM + d];
    float mean = s * (1.0f / NTOT);
    float var  = q * (1.0f / NTOT) - mean * mean;
    float sc = rsqrtf(var + 1e-5f) * gamma[layer * DM + d];
    scsh[d] = sc;
    scsh[DM + d] = beta[layer * DM + d] - mean * sc;
}

// ---------------------------------------------------------------------------
// 6) head
// ---------------------------------------------------------------------------
__global__ __launch_bounds__(128) void head_kernel(
    const __hip_bfloat16* __restrict__ Ub, const float* __restrict__ scsh,
    const float* __restrict__ W1, const float* __restrict__ b1,
    const float* __restrict__ W2, const float* __restrict__ b2,
    float* __restrict__ out) {
    int hh = blockIdx.x;
    int b  = blockIdx.y;
    int j  = threadIdx.x;
    int l  = (L_ - 1) + hh;
    const __hip_bfloat16* urow = Ub + ((size_t)b * DM) * LTR + l;
    float a = b1[j];
    for (int k = 0; k < DM; ++k) {
        float hn = fmaf(scsh[k], __bfloat162float(urow[(size_t)k * LTR]), scsh[DM + k]);
        a = fmaf(hn, W1[k * 128 + j], a);
    }
    float hs = a * sigmoidf_(a);
    float v = hs * W2[j];
    v += __shfl_xor(v, 1);
    v += __shfl_xor(v, 2);
    v += __shfl_xor(v, 4);
    v += __shfl_xor(v, 8);
    v += __shfl_xor(v, 16);
    v += __shfl_xor(v, 32);
    __shared__ float partial[2];
    if ((j & 63) == 0) partial[j >> 6] = v;
    __syncthreads();
    if (j == 0) out[b * H_ + hh] = partial[0] + partial[1] + b2[0];
}

// ---------------------------------------------------------------------------
extern "C" void kernel_launch(void* const* d_in, const int* in_sizes, int n_in,
                              void* d_out, int out_size, void* d_ws, size_t ws_size,
                              hipStream_t stream) {
    (void)in_sizes; (void)n_in; (void)out_size; (void)ws_size;
    const float* x_past      = (const float*)d_in[0];
    const float* noisy       = (const float*)d_in[1];
    const float* t_in        = (const float*)d_in[2];
    const float* x_future    = (const float*)d_in[3];
    const float* static_attr = (const float*)d_in[4];
    const float* freqs       = (const float*)d_in[5];
    const float* phases      = (const float*)d_in[6];
    const float* in_W        = (const float*)d_in[7];
    const float* in_b        = (const float*)d_in[8];
    const float* tm_W1       = (const float*)d_in[9];
    const float* tm_b1       = (const float*)d_in[10];
    const float* tm_W2       = (const float*)d_in[11];
    const float* tm_b2       = (const float*)d_in[12];
    const float* log_dt      = (const float*)d_in[13];
    const float* A_re        = (const float*)d_in[14];
    const float* A_im        = (const float*)d_in[15];
    const float* C_re        = (const float*)d_in[16];
    const float* C_im        = (const float*)d_in[17];
    const float* Dp          = (const float*)d_in[18];
    const float* out_W       = (const float*)d_in[19];
    const float* out_b       = (const float*)d_in[20];
    const float* bn_gamma    = (const float*)d_in[21];
    const float* bn_beta     = (const float*)d_in[22];
    const float* head_W1     = (const float*)d_in[23];
    const float* head_b1     = (const float*)d_in[24];
    const float* head_W2     = (const float*)d_in[25];
    const float* head_b2     = (const float*)d_in[26];

    char* ws = (char*)d_ws;
    const size_t UB_OFF = 1u << 20;
    const size_t UB_BYT = (size_t)B_ * DM * LTR * 2;
    const size_t R1_OFF = UB_OFF + UB_BYT;
    const size_t RB     = (size_t)256 * COLS * TCH * 2;
    const size_t R2_OFF = R1_OFF + RB;
    const size_t AB_OFF = R2_OFF + RB;
    const size_t AB_BYT = (size_t)256 * TCH * 256 * 2;
    const size_t SA_OFF = AB_OFF + AB_BYT;
    const size_t SA_BYT = (size_t)256 * TCH * TCH * 2;
    const size_t WT_OFF = SA_OFF + SA_BYT;

    float*          tb    = (float*)(ws);
    float*          stats = (float*)(ws + (64 << 10));
    float*          scsh  = (float*)(ws + (96 << 10));
    float*          Rsh   = (float*)(ws + (128 << 10));
    float*          T1sh  = (float*)(ws + (256 << 10));
    __hip_bfloat16* Ub    = (__hip_bfloat16*)(ws + UB_OFF);
    __hip_bfloat16* R1    = (__hip_bfloat16*)(ws + R1_OFF);
    __hip_bfloat16* Ybt   = (__hip_bfloat16*)(ws + R2_OFF);
    __hip_bfloat16* Abig  = (__hip_bfloat16*)(ws + AB_OFF);
    __hip_bfloat16* SA    = (__hip_bfloat16*)(ws + SA_OFF);
    __hip_bfloat16* Wtp   = (__hip_bfloat16*)(ws + WT_OFF);

    time_mlp_kernel<<<dim3(B_), 256, 0, stream>>>(
        t_in, freqs, phases, tm_W1, tm_b1, tm_W2, tm_b2, tb);

    wt_prep_kernel<<<dim3(NL * 256), 256, 0, stream>>>(out_W, Wtp);

    input_proj_kernel<<<dim3(9, B_), 256, 0, stream>>>(
        x_past, noisy, x_future, static_attr, in_W, in_b, tb, Ub);

    for (int layer = 0; layer < NL; ++layer) {
        prep_kernel<<<dim3(256), 256, 0, stream>>>(
            log_dt, A_re, A_im, C_re, C_im, Dp, bn_gamma, bn_beta,
            stats, scsh, Abig, SA, Rsh, T1sh, layer);
        sgemm_kernel<<<dim3(768), 256, 0, stream>>>(Ub, SA, Rsh, R1);
        carry_kernel<<<dim3(256, B_), 64, 0, stream>>>(
            R1, log_dt, A_re, A_im, layer);
        mainscan_kernel<<<dim3(768), 256, 0, stream>>>(Ub, R1, Abig, T1sh, Ybt);
        gemm_glu_mfma_kernel<<<dim3(2176), 256, 0, stream>>>(
            Ybt, Ub, Wtp, out_b, scsh, stats, layer);
    }

    statsfin_kernel<<<dim3(1), 256, 0, stream>>>(
        stats, bn_gamma, bn_beta, scsh, NL - 1);

    head_kernel<<<dim3(H_, B_), 128, 0, stream>>>(
        Ub, scsh, head_W1, head_b1, head_W2, head_b2, (float*)d_out);
}